// Round 1
// baseline (358.135 us; speedup 1.0000x reference)
//
#include <hip/hip_runtime.h>
#include <hip/hip_bf16.h>
#include <math.h>

// Problem constants (MemN2N): B=256, M=50, L=50, V=50257, D=128, HOPS=3
#define PB   256
#define PM   50
#define PL   50
#define PV   50257
#define PD   128
#define PBM  (PB * PM)              // 12800
#define TS   ((size_t)PV * PD)      // one embedding table, elements
#define PEC  0.000625f              // 4/(D*L) = 4/6400

// -------------------------------------------------------------------------
// Kernel 1: M_k[b,m,d] = sum_l emb[k][x_e[b,m,l]][d] * pe(l,d), k=0..3
// One block per (b,m). 128 threads = 4 tables x 32 lanes x float4.
// -------------------------------------------------------------------------
__global__ __launch_bounds__(128) void k_gather(const int* __restrict__ xe,
                                                const float* __restrict__ emb,
                                                float* __restrict__ Mw) {
    const int bm = blockIdx.x;       // b*50 + m
    const int t  = threadIdx.x;
    const int k  = t >> 5;           // table 0..3
    const int d4 = (t & 31) * 4;     // feature base

    __shared__ int sidx[PL];
    if (t < PL) sidx[t] = xe[(size_t)bm * PL + t];
    __syncthreads();

    const float dd0 = (float)(d4 + 0) - 63.0f;
    const float dd1 = (float)(d4 + 1) - 63.0f;
    const float dd2 = (float)(d4 + 2) - 63.0f;
    const float dd3 = (float)(d4 + 3) - 63.0f;

    float a0 = 0.f, a1 = 0.f, a2 = 0.f, a3 = 0.f;
    const float* tab = emb + (size_t)k * TS;

    #pragma unroll 10
    for (int l = 0; l < PL; ++l) {
        const float fl = PEC * ((float)l - 24.0f);
        const float4 v = *reinterpret_cast<const float4*>(
            tab + (size_t)sidx[l] * PD + d4);
        a0 += (1.0f + fl * dd0) * v.x;
        a1 += (1.0f + fl * dd1) * v.y;
        a2 += (1.0f + fl * dd2) * v.z;
        a3 += (1.0f + fl * dd3) * v.w;
    }

    float4 out = make_float4(a0, a1, a2, a3);
    *reinterpret_cast<float4*>(
        Mw + ((size_t)k * PBM + bm) * PD + d4) = out;
}

// -------------------------------------------------------------------------
// Kernel 2: per-b: u = sum_l emb[0][x_q[b,l]]*pe ; then 3 hops entirely
// in one block (scores -> softmax(50) -> o -> u += o). 256 blocks x 128 thr.
// -------------------------------------------------------------------------
__global__ __launch_bounds__(128) void k_hops(const int* __restrict__ xq,
                                              const float* __restrict__ emb,
                                              const float* __restrict__ Mw,
                                              float* __restrict__ u) {
    const int b = blockIdx.x;
    const int t = threadIdx.x;

    __shared__ float us[PD];
    __shared__ float ps[64];
    __shared__ int   sidx[PL];

    if (t < PL) sidx[t] = xq[(size_t)b * PL + t];
    __syncthreads();

    // u from query embedding (table 0)
    {
        const float dd = (float)t - 63.0f;
        float acc = 0.f;
        #pragma unroll 10
        for (int l = 0; l < PL; ++l) {
            const float pe = 1.0f + PEC * dd * ((float)l - 24.0f);
            acc += pe * emb[(size_t)sidx[l] * PD + t];
        }
        us[t] = acc;
    }
    __syncthreads();

    const int lane = t & 63;
    const int wave = t >> 6;

    for (int hop = 0; hop < 3; ++hop) {
        const float* Ma = Mw + ((size_t)hop * PBM + (size_t)b * PM) * PD;
        const float* Mc = Ma + (size_t)PBM * PD;

        // scores: each wave takes every other m
        for (int m = wave; m < PM; m += 2) {
            const float* row = Ma + (size_t)m * PD;
            float part = row[lane] * us[lane] + row[lane + 64] * us[lane + 64];
            #pragma unroll
            for (int off = 32; off > 0; off >>= 1)
                part += __shfl_down(part, off);
            if (lane == 0) ps[m] = part;
        }
        __syncthreads();

        // softmax over 50 scores (wave 0)
        if (wave == 0) {
            float s = (lane < PM) ? ps[lane] : -INFINITY;
            float mx = s;
            #pragma unroll
            for (int off = 32; off > 0; off >>= 1)
                mx = fmaxf(mx, __shfl_xor(mx, off));
            float e = (lane < PM) ? expf(s - mx) : 0.f;
            float sm = e;
            #pragma unroll
            for (int off = 32; off > 0; off >>= 1)
                sm += __shfl_xor(sm, off);
            if (lane < PM) ps[lane] = e / sm;
        }
        __syncthreads();

        // o[d] = sum_m p[m] * Mc[m][d]; u += o
        float o = 0.f;
        #pragma unroll 10
        for (int m = 0; m < PM; ++m)
            o += ps[m] * Mc[(size_t)m * PD + t];
        us[t] += o;
        __syncthreads();
    }

    u[(size_t)b * PD + t] = us[t];
}

// -------------------------------------------------------------------------
// Kernel 3: logits = u @ W  -> d_out.  fp32 SGEMM, 64x64 tile, BK=32,
// 4x4 register tile, 256 threads. (No fp32 MFMA on CDNA4 -> vector ALU.)
// -------------------------------------------------------------------------
__global__ __launch_bounds__(256) void k_gemm(const float* __restrict__ A,
                                              const float* __restrict__ W,
                                              float* __restrict__ C) {
    const int bn = blockIdx.x;       // 786 col tiles
    const int bm = blockIdx.y;       // 4 row tiles
    const int t  = threadIdx.x;
    const int tx = t & 15;
    const int ty = t >> 4;

    __shared__ __align__(16) float As[32][68];  // [k][row], pad->16B-aligned rows
    __shared__ __align__(16) float Ws[32][68];  // [k][col]

    float acc[4][4] = {};
    const int colBase = bn * 64;
    const int rowBase = bm * 64;

    for (int kc = 0; kc < PD; kc += 32) {
        // stage A tile: 64 rows x 32 k
        #pragma unroll
        for (int i = 0; i < 8; ++i) {
            const int e = t + i * 256;
            const int r = e >> 5, k = e & 31;
            As[k][r] = A[(size_t)(rowBase + r) * PD + kc + k];
        }
        // stage W tile: 32 k x 64 cols (guard last tile)
        #pragma unroll
        for (int i = 0; i < 8; ++i) {
            const int e = t + i * 256;
            const int k = e >> 6, c = e & 63;
            const int gc = colBase + c;
            Ws[k][c] = (gc < PV) ? W[(size_t)(kc + k) * PV + gc] : 0.f;
        }
        __syncthreads();

        #pragma unroll
        for (int kk = 0; kk < 32; ++kk) {
            const float4 av = *reinterpret_cast<const float4*>(&As[kk][ty * 4]);
            const float4 wv = *reinterpret_cast<const float4*>(&Ws[kk][tx * 4]);
            const float a_[4] = {av.x, av.y, av.z, av.w};
            const float w_[4] = {wv.x, wv.y, wv.z, wv.w};
            #pragma unroll
            for (int i = 0; i < 4; ++i)
                #pragma unroll
                for (int j = 0; j < 4; ++j)
                    acc[i][j] += a_[i] * w_[j];
        }
        __syncthreads();
    }

    // scalar stores (row*V is not 16B-aligned since V is odd)
    #pragma unroll
    for (int i = 0; i < 4; ++i) {
        const int r  = rowBase + ty * 4 + i;
        const int c0 = colBase + tx * 4;
        #pragma unroll
        for (int j = 0; j < 4; ++j) {
            const int c = c0 + j;
            if (c < PV) C[(size_t)r * PV + c] = acc[i][j];
        }
    }
}

// -------------------------------------------------------------------------
// Kernel 4: per-row max & sum(exp) over V. 256 blocks x 1024 threads.
// -------------------------------------------------------------------------
__global__ __launch_bounds__(1024) void k_rowstats(const float* __restrict__ logits,
                                                   float* __restrict__ stats) {
    const int b = blockIdx.x;
    const int t = threadIdx.x;
    __shared__ float red[1024];
    const float* row = logits + (size_t)b * PV;

    float mx = -INFINITY;
    for (int i = t; i < PV; i += 1024) mx = fmaxf(mx, row[i]);
    red[t] = mx;
    __syncthreads();
    for (int s = 512; s > 0; s >>= 1) {
        if (t < s) red[t] = fmaxf(red[t], red[t + s]);
        __syncthreads();
    }
    mx = red[0];
    __syncthreads();

    float sum = 0.f;
    for (int i = t; i < PV; i += 1024) sum += expf(row[i] - mx);
    red[t] = sum;
    __syncthreads();
    for (int s = 512; s > 0; s >>= 1) {
        if (t < s) red[t] += red[t + s];
        __syncthreads();
    }
    if (t == 0) { stats[2 * b] = mx; stats[2 * b + 1] = red[0]; }
}

// -------------------------------------------------------------------------
// Kernel 5: out = exp(x - max) / sum, in place.
// -------------------------------------------------------------------------
__global__ __launch_bounds__(256) void k_norm(float* __restrict__ out,
                                              const float* __restrict__ stats) {
    const int b = blockIdx.y;
    const int i = blockIdx.x * 256 + threadIdx.x;
    if (i >= PV) return;
    const float mx   = stats[2 * b];
    const float rinv = 1.0f / stats[2 * b + 1];
    const size_t idx = (size_t)b * PV + i;
    out[idx] = expf(out[idx] - mx) * rinv;
}

// -------------------------------------------------------------------------
extern "C" void kernel_launch(void* const* d_in, const int* in_sizes, int n_in,
                              void* d_out, int out_size, void* d_ws, size_t ws_size,
                              hipStream_t stream) {
    const int*   x_e = (const int*)d_in[0];    // [B, M, L]
    const int*   x_q = (const int*)d_in[1];    // [B, L]
    const float* emb = (const float*)d_in[2];  // [4, V, D]
    const float* W   = (const float*)d_in[3];  // [D, V]
    float*       out = (float*)d_out;          // [B, V]

    // workspace layout
    float* u_ws  = (float*)d_ws;               // 256*128            = 32768 f
    float* M_ws  = u_ws + PB * PD;             // 4*12800*128        = 6553600 f
    float* stats = M_ws + 4 * (size_t)PBM * PD; // 512 f
    (void)ws_size; (void)n_in; (void)in_sizes; (void)out_size;

    // 1. gather-sum all 4 memory tables
    k_gather<<<dim3(PBM), dim3(128), 0, stream>>>(x_e, emb, M_ws);
    // 2. u + 3 hops (per-b independent)
    k_hops<<<dim3(PB), dim3(128), 0, stream>>>(x_q, emb, M_ws, u_ws);
    // 3. logits = u @ W  -> d_out
    k_gemm<<<dim3((PV + 63) / 64, PB / 64), dim3(256), 0, stream>>>(u_ws, W, out);
    // 4. row softmax stats
    k_rowstats<<<dim3(PB), dim3(1024), 0, stream>>>(out, stats);
    // 5. normalize in place
    k_norm<<<dim3((PV + 255) / 256, PB), dim3(256), 0, stream>>>(out, stats);
}

// Round 4
// 336.296 us; speedup vs baseline: 1.0649x; 1.0649x over previous
//
#include <hip/hip_runtime.h>
#include <hip/hip_bf16.h>
#include <hip/hip_fp16.h>
#include <math.h>

// Problem constants (MemN2N): B=256, M=50, L=50, V=50257, D=128, HOPS=3
#define PB   256
#define PM   50
#define PL   50
#define PV   50257
#define PD   128
#define PBM  (PB * PM)              // 12800
#define TS   ((size_t)PV * PD)      // one embedding table, elements
#define PEC  0.000625f              // 4/(D*L) = 4/6400
#define NT   786                    // ceil(PV/64) column tiles
#define PVP  (NT * 64)              // 50304 padded vocab

typedef _Float16 f16x8 __attribute__((ext_vector_type(8)));
typedef float    f32x4 __attribute__((ext_vector_type(4)));

// -------------------------------------------------------------------------
// Kernel 1: M_k[b,m,d] = sum_l emb[k][x_e[b,m,l]][d] * pe(l,d), k=0..3
// One block per (b,m). 128 threads = 4 tables x 32 lanes x float4. fp32.
// -------------------------------------------------------------------------
__global__ __launch_bounds__(128) void k_gather(const int* __restrict__ xe,
                                                const float* __restrict__ emb,
                                                float* __restrict__ Mw) {
    const int bm = blockIdx.x;
    const int t  = threadIdx.x;
    const int k  = t >> 5;
    const int d4 = (t & 31) * 4;

    __shared__ int sidx[PL];
    if (t < PL) sidx[t] = xe[(size_t)bm * PL + t];
    __syncthreads();

    const float dd0 = (float)(d4 + 0) - 63.0f;
    const float dd1 = (float)(d4 + 1) - 63.0f;
    const float dd2 = (float)(d4 + 2) - 63.0f;
    const float dd3 = (float)(d4 + 3) - 63.0f;

    float a0 = 0.f, a1 = 0.f, a2 = 0.f, a3 = 0.f;
    const float* tab = emb + (size_t)k * TS;

    #pragma unroll 10
    for (int l = 0; l < PL; ++l) {
        const float fl = PEC * ((float)l - 24.0f);
        const float4 v = *reinterpret_cast<const float4*>(
            tab + (size_t)sidx[l] * PD + d4);
        a0 += (1.0f + fl * dd0) * v.x;
        a1 += (1.0f + fl * dd1) * v.y;
        a2 += (1.0f + fl * dd2) * v.z;
        a3 += (1.0f + fl * dd3) * v.w;
    }

    // non-temporal: protect the L3-resident embedding tables
    const f32x4 o = {a0, a1, a2, a3};
    __builtin_nontemporal_store(o,
        reinterpret_cast<f32x4*>(Mw + ((size_t)k * PBM + bm) * PD + d4));
}

// -------------------------------------------------------------------------
// Kernel 2: per-b: u = query embedding sum (fp32), then 3 hops. Writes u as
// fp16 row-major [B][D] for the MFMA GEMM. 256 blocks x 128 threads.
// -------------------------------------------------------------------------
__global__ __launch_bounds__(128) void k_hops(const int* __restrict__ xq,
                                              const float* __restrict__ emb,
                                              const float* __restrict__ Mw,
                                              _Float16* __restrict__ uh) {
    const int b = blockIdx.x;
    const int t = threadIdx.x;

    __shared__ float us[PD];
    __shared__ float ps[64];
    __shared__ int   sidx[PL];

    if (t < PL) sidx[t] = xq[(size_t)b * PL + t];
    __syncthreads();

    {
        const float dd = (float)t - 63.0f;
        float acc = 0.f;
        #pragma unroll 10
        for (int l = 0; l < PL; ++l) {
            const float pe = 1.0f + PEC * dd * ((float)l - 24.0f);
            acc += pe * emb[(size_t)sidx[l] * PD + t];
        }
        us[t] = acc;
    }
    __syncthreads();

    const int lane = t & 63;
    const int wave = t >> 6;

    for (int hop = 0; hop < 3; ++hop) {
        const float* Ma = Mw + ((size_t)hop * PBM + (size_t)b * PM) * PD;
        const float* Mc = Ma + (size_t)PBM * PD;

        for (int m = wave; m < PM; m += 2) {
            const float* row = Ma + (size_t)m * PD;
            float part = row[lane] * us[lane] + row[lane + 64] * us[lane + 64];
            #pragma unroll
            for (int off = 32; off > 0; off >>= 1)
                part += __shfl_down(part, off);
            if (lane == 0) ps[m] = part;
        }
        __syncthreads();

        if (wave == 0) {
            float s = (lane < PM) ? ps[lane] : -INFINITY;
            float mx = s;
            #pragma unroll
            for (int off = 32; off > 0; off >>= 1)
                mx = fmaxf(mx, __shfl_xor(mx, off));
            float e = (lane < PM) ? __expf(s - mx) : 0.f;
            float sm = e;
            #pragma unroll
            for (int off = 32; off > 0; off >>= 1)
                sm += __shfl_xor(sm, off);
            if (lane < PM) ps[lane] = e / sm;
        }
        __syncthreads();

        float o = 0.f;
        #pragma unroll 10
        for (int m = 0; m < PM; ++m)
            o += ps[m] * Mc[(size_t)m * PD + t];
        us[t] += o;
        __syncthreads();
    }

    uh[(size_t)b * PD + t] = (_Float16)us[t];
}

// -------------------------------------------------------------------------
// Kernel 3: W [128][V] fp32 -> Wt [PVP][128] fp16 (transposed, zero-padded).
// 786 blocks x 256 threads, 64 cols per block, LDS transpose.
// -------------------------------------------------------------------------
__global__ __launch_bounds__(256) void k_convW(const float* __restrict__ W,
                                               _Float16* __restrict__ Wt) {
    const int c0 = blockIdx.x * 64;
    const int t  = threadIdx.x;
    __shared__ float ls[PD][65];

    #pragma unroll
    for (int i = 0; i < 32; ++i) {
        const int e = t + i * 256;       // 8192 elems: k = e/64, c = e%64
        const int k = e >> 6, c = e & 63;
        const int gc = c0 + c;
        ls[k][c] = (gc < PV) ?
            __builtin_nontemporal_load(W + (size_t)k * PV + gc) : 0.f;
    }
    __syncthreads();

    #pragma unroll
    for (int i = 0; i < 4; ++i) {
        const int ch = t + i * 256;      // 1024 chunks: c = ch/16, k0 = (ch%16)*8
        const int c  = ch >> 4, k0 = (ch & 15) * 8;
        f16x8 v;
        #pragma unroll
        for (int j = 0; j < 8; ++j) v[j] = (_Float16)ls[k0 + j][c];
        __builtin_nontemporal_store(v,
            reinterpret_cast<f16x8*>(Wt + (size_t)(c0 + c) * PD + k0));
    }
}

// -------------------------------------------------------------------------
// Kernel 4: logits = uh @ Wt^T via fp16 MFMA, direct-global fragments.
// Block = 256 thr (4 waves), 256 rows x 64 cols per block, grid = 786.
// Fused per-tile softmax partials (rowmax, sum exp) -> part[tile][row].
// -------------------------------------------------------------------------
__global__ __launch_bounds__(256) void k_gemm_mfma(const _Float16* __restrict__ uh,
                                                   const _Float16* __restrict__ Wt,
                                                   float* __restrict__ C,
                                                   float* __restrict__ part) {
    const int tile    = blockIdx.x;
    const int colBase = tile * 64;
    const int w       = threadIdx.x >> 6;
    const int l       = threadIdx.x & 63;
    const int lrow    = l & 15;
    const int lk      = (l >> 4) * 8;
    const int rowBase = w * 64;

    f32x4 acc[4][4];
    #pragma unroll
    for (int i = 0; i < 4; ++i)
        #pragma unroll
        for (int j = 0; j < 4; ++j)
            acc[i][j] = (f32x4){0.f, 0.f, 0.f, 0.f};

    #pragma unroll
    for (int ks = 0; ks < 4; ++ks) {
        const int k0 = ks * 32 + lk;
        f16x8 a[4], b[4];
        #pragma unroll
        for (int mi = 0; mi < 4; ++mi)
            a[mi] = *reinterpret_cast<const f16x8*>(
                uh + (size_t)(rowBase + mi * 16 + lrow) * PD + k0);
        #pragma unroll
        for (int ni = 0; ni < 4; ++ni)
            b[ni] = __builtin_nontemporal_load(
                reinterpret_cast<const f16x8*>(
                    Wt + (size_t)(colBase + ni * 16 + lrow) * PD + k0));
        #pragma unroll
        for (int mi = 0; mi < 4; ++mi)
            #pragma unroll
            for (int ni = 0; ni < 4; ++ni)
                acc[mi][ni] = __builtin_amdgcn_mfma_f32_16x16x32_f16(
                    a[mi], b[ni], acc[mi][ni], 0, 0, 0);
    }

    // C/D layout: col = lane&15 (lrow), row = (lane>>4)*4 + reg
    const int rquad = (l >> 4) * 4;
    #pragma unroll
    for (int mi = 0; mi < 4; ++mi) {
        #pragma unroll
        for (int q = 0; q < 4; ++q) {
            const int row = rowBase + mi * 16 + rquad + q;
            float v[4];
            float mx = -INFINITY;
            #pragma unroll
            for (int j = 0; j < 4; ++j) {
                const int col = colBase + j * 16 + lrow;
                v[j] = acc[mi][j][q];
                if (col < PV) {
                    __builtin_nontemporal_store(v[j], C + (size_t)row * PV + col);
                    mx = fmaxf(mx, v[j]);
                } else {
                    v[j] = -INFINITY;
                }
            }
            #pragma unroll
            for (int msk = 1; msk < 16; msk <<= 1)
                mx = fmaxf(mx, __shfl_xor(mx, msk));
            float se = 0.f;
            #pragma unroll
            for (int j = 0; j < 4; ++j)
                if (v[j] > -INFINITY) se += __expf(v[j] - mx);
            #pragma unroll
            for (int msk = 1; msk < 16; msk <<= 1)
                se += __shfl_xor(se, msk);
            if (lrow == 0) {
                part[((size_t)tile * PB + row) * 2 + 0] = mx;
                part[((size_t)tile * PB + row) * 2 + 1] = se;
            }
        }
    }
}

// -------------------------------------------------------------------------
// Kernel 5: merge per-tile partials -> stats[2b] = rowmax, [2b+1] = rowsum.
// 256 blocks x 64 threads, online softmax merge.
// -------------------------------------------------------------------------
__global__ __launch_bounds__(64) void k_merge(const float* __restrict__ part,
                                              float* __restrict__ stats) {
    const int b = blockIdx.x;
    const int l = threadIdx.x;
    float M = -INFINITY, S = 0.f;
    for (int t = l; t < NT; t += 64) {
        const float m = part[((size_t)t * PB + b) * 2 + 0];
        const float s = part[((size_t)t * PB + b) * 2 + 1];
        const float nM = fmaxf(M, m);
        S = S * __expf(M - nM) + s * __expf(m - nM);
        M = nM;
    }
    #pragma unroll
    for (int msk = 32; msk > 0; msk >>= 1) {
        const float m2 = __shfl_xor(M, msk);
        const float s2 = __shfl_xor(S, msk);
        const float nM = fmaxf(M, m2);
        S = S * __expf(M - nM) + s2 * __expf(m2 - nM);
        M = nM;
    }
    if (l == 0) { stats[2 * b] = M; stats[2 * b + 1] = S; }
}

// -------------------------------------------------------------------------
// Kernel 6: out = exp(x - max)/sum in place. 256 blocks x 512 threads.
// -------------------------------------------------------------------------
__global__ __launch_bounds__(512) void k_norm(float* __restrict__ out,
                                              const float* __restrict__ stats) {
    const int b = blockIdx.x;
    const int t = threadIdx.x;
    const float mx   = stats[2 * b];
    const float rinv = 1.0f / stats[2 * b + 1];
    float* row = out + (size_t)b * PV;

    const int head = (4 - (b & 3)) & 3;          // (b*PV)%4 == b%4 since PV%4==1
    const int n4   = (PV - head) >> 2;
    const int tail = PV - head - n4 * 4;
    f32x4* v = reinterpret_cast<f32x4*>(row + head);

    if (t < head) row[t] = __expf(row[t] - mx) * rinv;
    for (int i = t; i < n4; i += 512) {
        f32x4 x = __builtin_nontemporal_load(v + i);
        x.x = __expf(x.x - mx) * rinv;
        x.y = __expf(x.y - mx) * rinv;
        x.z = __expf(x.z - mx) * rinv;
        x.w = __expf(x.w - mx) * rinv;
        __builtin_nontemporal_store(x, v + i);
    }
    if (t < tail) {
        const int i = head + n4 * 4 + t;
        row[i] = __expf(row[i] - mx) * rinv;
    }
}

// -------------------------------------------------------------------------
extern "C" void kernel_launch(void* const* d_in, const int* in_sizes, int n_in,
                              void* d_out, int out_size, void* d_ws, size_t ws_size,
                              hipStream_t stream) {
    const int*   x_e = (const int*)d_in[0];    // [B, M, L]
    const int*   x_q = (const int*)d_in[1];    // [B, L]
    const float* emb = (const float*)d_in[2];  // [4, V, D]
    const float* W   = (const float*)d_in[3];  // [D, V]
    float*       out = (float*)d_out;          // [B, V] (logits then probs)
    (void)n_in; (void)in_sizes; (void)out_size; (void)ws_size;

    // workspace layout (all offsets 256B-aligned)
    char* p = (char*)d_ws;
    float*    M_ws  = (float*)p;                p += (size_t)4 * PBM * PD * 4;   // 26.2 MB
    _Float16* uh    = (_Float16*)p;             p += (size_t)PB * PD * 2;        // 64 KB
    _Float16* Wt    = (_Float16*)p;             p += (size_t)PVP * PD * 2;       // 12.9 MB
    float*    part  = (float*)p;                p += (size_t)NT * PB * 2 * 4;    // 1.6 MB
    float*    stats = (float*)p;

    k_gather<<<dim3(PBM), dim3(128), 0, stream>>>(x_e, emb, M_ws);
    k_hops  <<<dim3(PB),  dim3(128), 0, stream>>>(x_q, emb, M_ws, uh);
    k_convW <<<dim3(NT),  dim3(256), 0, stream>>>(W, Wt);
    k_gemm_mfma<<<dim3(NT), dim3(256), 0, stream>>>(uh, Wt, out, part);
    k_merge <<<dim3(PB),  dim3(64),  0, stream>>>(part, stats);
    k_norm  <<<dim3(PB),  dim3(512), 0, stream>>>(out, stats);
}

// Round 5
// 293.882 us; speedup vs baseline: 1.2186x; 1.1443x over previous
//
#include <hip/hip_runtime.h>
#include <hip/hip_bf16.h>
#include <hip/hip_fp16.h>
#include <math.h>

// Problem constants (MemN2N): B=256, M=50, L=50, V=50257, D=128, HOPS=3
#define PB   256
#define PM   50
#define PL   50
#define PV   50257
#define PD   128
#define PBM  (PB * PM)              // 12800
#define TS   ((size_t)PV * PD)      // one embedding table, elements
#define PEC  0.000625f              // 4/(D*L) = 4/6400
#define NT   786                    // ceil(PV/64) column tiles
#define PVP  (NT * 64)              // 50304 padded vocab

typedef _Float16 f16x8 __attribute__((ext_vector_type(8)));
typedef float    f32x4 __attribute__((ext_vector_type(4)));

// -------------------------------------------------------------------------
// Kernel 1: table-phased gather. grid = 4 tables x 6400 (2 bm per block),
// dispatched table-major so the concurrent hot set is ONE 25.7 MB table.
// Block: 256 thr = 2 bm-units x (4 l-subgroups x 32 lanes x float4).
// -------------------------------------------------------------------------
__global__ __launch_bounds__(256) void k_gather(const int* __restrict__ xe,
                                                const float* __restrict__ emb,
                                                float* __restrict__ Mw) {
    const int blk = blockIdx.x;          // 0..25599, table-major
    const int k   = blk / 6400;          // table 0..3
    const int bm0 = (blk % 6400) * 2;
    const int sub = threadIdx.x >> 7;    // bm unit 0/1
    const int tt  = threadIdx.x & 127;
    const int ls  = tt >> 5;             // l subgroup 0..3
    const int c   = tt & 31;
    const int d4  = c * 4;
    const int bm  = bm0 + sub;

    __shared__ int   sidx[2][PL];
    __shared__ f32x4 red[2][3][32];

    if (threadIdx.x < 2 * PL)
        ((int*)sidx)[threadIdx.x] = xe[(size_t)bm0 * PL + threadIdx.x];
    __syncthreads();

    const float dd0 = (float)(d4 + 0) - 63.0f;
    const float dd1 = (float)(d4 + 1) - 63.0f;
    const float dd2 = (float)(d4 + 2) - 63.0f;
    const float dd3 = (float)(d4 + 3) - 63.0f;

    float a0 = 0.f, a1 = 0.f, a2 = 0.f, a3 = 0.f;
    const float* tab = emb + (size_t)k * TS;

    #pragma unroll
    for (int i = 0; i < 12; ++i) {
        const int   l  = ls + 4 * i;
        const float fl = PEC * ((float)l - 24.0f);
        const float4 v = *reinterpret_cast<const float4*>(
            tab + (size_t)sidx[sub][l] * PD + d4);
        a0 += (1.0f + fl * dd0) * v.x;
        a1 += (1.0f + fl * dd1) * v.y;
        a2 += (1.0f + fl * dd2) * v.z;
        a3 += (1.0f + fl * dd3) * v.w;
    }
    if (ls < 2) {                        // tail: l = 48, 49
        const int   l  = 48 + ls;
        const float fl = PEC * ((float)l - 24.0f);
        const float4 v = *reinterpret_cast<const float4*>(
            tab + (size_t)sidx[sub][l] * PD + d4);
        a0 += (1.0f + fl * dd0) * v.x;
        a1 += (1.0f + fl * dd1) * v.y;
        a2 += (1.0f + fl * dd2) * v.z;
        a3 += (1.0f + fl * dd3) * v.w;
    }

    if (ls > 0) {
        red[sub][ls - 1][c] = (f32x4){a0, a1, a2, a3};
    }
    __syncthreads();
    if (ls == 0) {
        f32x4 s = {a0, a1, a2, a3};
        s += red[sub][0][c];
        s += red[sub][1][c];
        s += red[sub][2][c];
        __builtin_nontemporal_store(s,
            reinterpret_cast<f32x4*>(Mw + ((size_t)k * PBM + bm) * PD + d4));
    }
}

// -------------------------------------------------------------------------
// Kernel 2: per-b u + 3 hops. 256 blocks x 512 threads (8 waves):
// l/m work split 4-8 ways, LDS tree reduction.
// -------------------------------------------------------------------------
__global__ __launch_bounds__(512) void k_hops(const int* __restrict__ xq,
                                              const float* __restrict__ emb,
                                              const float* __restrict__ Mw,
                                              _Float16* __restrict__ uh) {
    const int b = blockIdx.x;
    const int t = threadIdx.x;
    const int g = t >> 7;        // group 0..3
    const int d = t & 127;

    __shared__ float us[PD];
    __shared__ float ps[64];
    __shared__ float red[4][PD];
    __shared__ int   sidx[PL];

    if (t < PL) sidx[t] = xq[(size_t)b * PL + t];
    __syncthreads();

    // u = query embedding sum (l split over 4 groups)
    {
        const float dd = (float)d - 63.0f;
        float acc = 0.f;
        for (int l = g; l < PL; l += 4)
            acc += (1.0f + PEC * dd * ((float)l - 24.0f)) *
                   emb[(size_t)sidx[l] * PD + d];
        red[g][d] = acc;
    }
    __syncthreads();
    if (t < PD) us[t] = red[0][t] + red[1][t] + red[2][t] + red[3][t];
    __syncthreads();

    const int lane = t & 63;
    const int wave = t >> 6;

    for (int hop = 0; hop < 3; ++hop) {
        const float* Ma = Mw + ((size_t)hop * PBM + (size_t)b * PM) * PD;
        const float* Mc = Ma + (size_t)PBM * PD;

        // scores: m split over 8 waves
        for (int m = wave; m < PM; m += 8) {
            const float* row = Ma + (size_t)m * PD;
            float part = row[lane] * us[lane] + row[lane + 64] * us[lane + 64];
            #pragma unroll
            for (int off = 32; off > 0; off >>= 1)
                part += __shfl_down(part, off);
            if (lane == 0) ps[m] = part;
        }
        __syncthreads();

        // softmax over 50 scores (wave 0)
        if (wave == 0) {
            float s = (lane < PM) ? ps[lane] : -INFINITY;
            float mx = s;
            #pragma unroll
            for (int off = 32; off > 0; off >>= 1)
                mx = fmaxf(mx, __shfl_xor(mx, off));
            float e = (lane < PM) ? __expf(s - mx) : 0.f;
            float sm = e;
            #pragma unroll
            for (int off = 32; off > 0; off >>= 1)
                sm += __shfl_xor(sm, off);
            if (lane < PM) ps[lane] = e / sm;
        }
        __syncthreads();

        // o[d] = sum_m p[m]*Mc[m][d], m split over 4 groups
        {
            float o = 0.f;
            for (int m = g; m < PM; m += 4)
                o += ps[m] * Mc[(size_t)m * PD + d];
            red[g][d] = o;
        }
        __syncthreads();
        if (t < PD) us[t] += red[0][t] + red[1][t] + red[2][t] + red[3][t];
        __syncthreads();
    }

    if (t < PD) uh[(size_t)b * PD + t] = (_Float16)us[t];
}

// -------------------------------------------------------------------------
// Kernel 3: W [128][V] fp32 -> Wt [PVP][128] fp16 (transposed, zero-padded).
// -------------------------------------------------------------------------
__global__ __launch_bounds__(256) void k_convW(const float* __restrict__ W,
                                               _Float16* __restrict__ Wt) {
    const int c0 = blockIdx.x * 64;
    const int t  = threadIdx.x;
    __shared__ float ls[PD][65];

    #pragma unroll
    for (int i = 0; i < 32; ++i) {
        const int e = t + i * 256;
        const int k = e >> 6, c = e & 63;
        const int gc = c0 + c;
        ls[k][c] = (gc < PV) ?
            __builtin_nontemporal_load(W + (size_t)k * PV + gc) : 0.f;
    }
    __syncthreads();

    #pragma unroll
    for (int i = 0; i < 4; ++i) {
        const int ch = t + i * 256;
        const int c  = ch >> 4, k0 = (ch & 15) * 8;
        f16x8 v;
        #pragma unroll
        for (int j = 0; j < 8; ++j) v[j] = (_Float16)ls[k0 + j][c];
        __builtin_nontemporal_store(v,
            reinterpret_cast<f16x8*>(Wt + (size_t)(c0 + c) * PD + k0));
    }
}

// -------------------------------------------------------------------------
// Shared MFMA core: computes acc[4][4] (256 rows x 64 cols tile).
// -------------------------------------------------------------------------
__device__ __forceinline__ void gemm_core(const _Float16* __restrict__ uh,
                                          const _Float16* __restrict__ Wt,
                                          int colBase, int rowBase,
                                          int lrow, int lk,
                                          f32x4 acc[4][4]) {
    #pragma unroll
    for (int i = 0; i < 4; ++i)
        #pragma unroll
        for (int j = 0; j < 4; ++j)
            acc[i][j] = (f32x4){0.f, 0.f, 0.f, 0.f};

    #pragma unroll
    for (int ks = 0; ks < 4; ++ks) {
        const int k0 = ks * 32 + lk;
        f16x8 a[4], bfr[4];
        #pragma unroll
        for (int mi = 0; mi < 4; ++mi)
            a[mi] = *reinterpret_cast<const f16x8*>(
                uh + (size_t)(rowBase + mi * 16 + lrow) * PD + k0);
        #pragma unroll
        for (int ni = 0; ni < 4; ++ni)
            bfr[ni] = *reinterpret_cast<const f16x8*>(
                Wt + (size_t)(colBase + ni * 16 + lrow) * PD + k0);
        #pragma unroll
        for (int mi = 0; mi < 4; ++mi)
            #pragma unroll
            for (int ni = 0; ni < 4; ++ni)
                acc[mi][ni] = __builtin_amdgcn_mfma_f32_16x16x32_f16(
                    a[mi], bfr[ni], acc[mi][ni], 0, 0, 0);
    }
}

// -------------------------------------------------------------------------
// Kernel 4: GEMM pass 1 — per-tile softmax partials only (no logit store).
// -------------------------------------------------------------------------
__global__ __launch_bounds__(256) void k_gemm_stats(const _Float16* __restrict__ uh,
                                                    const _Float16* __restrict__ Wt,
                                                    float* __restrict__ part) {
    const int tile    = blockIdx.x;
    const int colBase = tile * 64;
    const int w       = threadIdx.x >> 6;
    const int l       = threadIdx.x & 63;
    const int lrow    = l & 15;
    const int lk      = (l >> 4) * 8;
    const int rowBase = w * 64;

    f32x4 acc[4][4];
    gemm_core(uh, Wt, colBase, rowBase, lrow, lk, acc);

    const int rquad = (l >> 4) * 4;
    #pragma unroll
    for (int mi = 0; mi < 4; ++mi) {
        #pragma unroll
        for (int q = 0; q < 4; ++q) {
            const int row = rowBase + mi * 16 + rquad + q;
            float v[4];
            float mx = -INFINITY;
            #pragma unroll
            for (int j = 0; j < 4; ++j) {
                const int col = colBase + j * 16 + lrow;
                v[j] = (col < PV) ? acc[mi][j][q] : -INFINITY;
                mx = fmaxf(mx, v[j]);
            }
            #pragma unroll
            for (int msk = 1; msk < 16; msk <<= 1)
                mx = fmaxf(mx, __shfl_xor(mx, msk));
            float se = 0.f;
            #pragma unroll
            for (int j = 0; j < 4; ++j)
                if (v[j] > -INFINITY) se += __expf(v[j] - mx);
            #pragma unroll
            for (int msk = 1; msk < 16; msk <<= 1)
                se += __shfl_xor(se, msk);
            if (lrow == 0) {
                part[((size_t)tile * PB + row) * 2 + 0] = mx;
                part[((size_t)tile * PB + row) * 2 + 1] = se;
            }
        }
    }
}

// -------------------------------------------------------------------------
// Kernel 5: merge per-tile partials -> stats[2b]=rowmax, [2b+1]=rowsum.
// -------------------------------------------------------------------------
__global__ __launch_bounds__(64) void k_merge(const float* __restrict__ part,
                                              float* __restrict__ stats) {
    const int b = blockIdx.x;
    const int l = threadIdx.x;
    float M = -INFINITY, S = 0.f;
    for (int t = l; t < NT; t += 64) {
        const float m = part[((size_t)t * PB + b) * 2 + 0];
        const float s = part[((size_t)t * PB + b) * 2 + 1];
        const float nM = fmaxf(M, m);
        S = S * __expf(M - nM) + s * __expf(m - nM);
        M = nM;
    }
    #pragma unroll
    for (int msk = 32; msk > 0; msk >>= 1) {
        const float m2 = __shfl_xor(M, msk);
        const float s2 = __shfl_xor(S, msk);
        const float nM = fmaxf(M, m2);
        S = S * __expf(M - nM) + s2 * __expf(m2 - nM);
        M = nM;
    }
    if (l == 0) { stats[2 * b] = M; stats[2 * b + 1] = S; }
}

// -------------------------------------------------------------------------
// Kernel 6: GEMM pass 2 — recompute logits, write probs = exp(v-M)/S.
// -------------------------------------------------------------------------
__global__ __launch_bounds__(256) void k_gemm_probs(const _Float16* __restrict__ uh,
                                                    const _Float16* __restrict__ Wt,
                                                    const float* __restrict__ stats,
                                                    float* __restrict__ out) {
    const int tile    = blockIdx.x;
    const int colBase = tile * 64;
    const int w       = threadIdx.x >> 6;
    const int l       = threadIdx.x & 63;
    const int lrow    = l & 15;
    const int lk      = (l >> 4) * 8;
    const int rowBase = w * 64;

    __shared__ float sM[PB], sR[PB];
    if (threadIdx.x < PB) {
        sM[threadIdx.x] = stats[2 * threadIdx.x];
        sR[threadIdx.x] = 1.0f / stats[2 * threadIdx.x + 1];
    }

    f32x4 acc[4][4];
    gemm_core(uh, Wt, colBase, rowBase, lrow, lk, acc);
    __syncthreads();

    const int rquad = (l >> 4) * 4;
    #pragma unroll
    for (int mi = 0; mi < 4; ++mi) {
        #pragma unroll
        for (int q = 0; q < 4; ++q) {
            const int row = rowBase + mi * 16 + rquad + q;
            const float mx   = sM[row];
            const float rinv = sR[row];
            #pragma unroll
            for (int j = 0; j < 4; ++j) {
                const int col = colBase + j * 16 + lrow;
                if (col < PV) {
                    const float p = __expf(acc[mi][j][q] - mx) * rinv;
                    __builtin_nontemporal_store(p, out + (size_t)row * PV + col);
                }
            }
        }
    }
}

// -------------------------------------------------------------------------
extern "C" void kernel_launch(void* const* d_in, const int* in_sizes, int n_in,
                              void* d_out, int out_size, void* d_ws, size_t ws_size,
                              hipStream_t stream) {
    const int*   x_e = (const int*)d_in[0];    // [B, M, L]
    const int*   x_q = (const int*)d_in[1];    // [B, L]
    const float* emb = (const float*)d_in[2];  // [4, V, D]
    const float* W   = (const float*)d_in[3];  // [D, V]
    float*       out = (float*)d_out;          // [B, V]
    (void)n_in; (void)in_sizes; (void)out_size; (void)ws_size;

    char* p = (char*)d_ws;
    float*    M_ws  = (float*)p;                p += (size_t)4 * PBM * PD * 4;   // 26.2 MB
    _Float16* uh    = (_Float16*)p;             p += (size_t)PB * PD * 2;        // 64 KB
    _Float16* Wt    = (_Float16*)p;             p += (size_t)PVP * PD * 2;       // 12.9 MB
    float*    part  = (float*)p;                p += (size_t)NT * PB * 2 * 4;    // 1.6 MB
    float*    stats = (float*)p;

    k_convW <<<dim3(NT),      dim3(256), 0, stream>>>(W, Wt);
    k_gather<<<dim3(4 * 6400), dim3(256), 0, stream>>>(x_e, emb, M_ws);
    k_hops  <<<dim3(PB),      dim3(512), 0, stream>>>(x_q, emb, M_ws, uh);
    k_gemm_stats<<<dim3(NT),  dim3(256), 0, stream>>>(uh, Wt, part);
    k_merge <<<dim3(PB),      dim3(64),  0, stream>>>(part, stats);
    k_gemm_probs<<<dim3(NT),  dim3(256), 0, stream>>>(uh, Wt, stats, out);
}

// Round 6
// 293.594 us; speedup vs baseline: 1.2198x; 1.0010x over previous
//
#include <hip/hip_runtime.h>
#include <hip/hip_bf16.h>
#include <hip/hip_fp16.h>
#include <math.h>

// Problem constants (MemN2N): B=256, M=50, L=50, V=50257, D=128, HOPS=3
#define PB   256
#define PM   50
#define PL   50
#define PV   50257
#define PD   128
#define PBM  (PB * PM)              // 12800
#define TS   ((size_t)PV * PD)      // one embedding table, elements
#define PEC  0.000625f              // 4/(D*L) = 4/6400
#define NT   786                    // ceil(PV/64) column tiles
#define PVP  (NT * 64)              // 50304 padded vocab
#define NCONV 786                   // convW blocks at the front of fused launch
#define NGB   3200                  // gather blocks per table (4 bm each)

typedef _Float16 f16x8 __attribute__((ext_vector_type(8)));
typedef float    f32x4 __attribute__((ext_vector_type(4)));

// -------------------------------------------------------------------------
// Kernel 1 (fused): blocks 0..785 transpose W -> Wt fp16; blocks 786.. do
// the table-phased gather with an 8-deep explicit load pipeline.
// Gather: 1 wave per bm (4 bm/block); lane: d4=(lane&31)*4, row-half h.
// -------------------------------------------------------------------------
__global__ __launch_bounds__(256, 8) void k_gather_conv(
        const int* __restrict__ xe, const float* __restrict__ emb,
        const float* __restrict__ W, float* __restrict__ Mw,
        _Float16* __restrict__ Wt) {
    __shared__ int   sidx[4][PL];
    __shared__ float ls[PD][17];

    const int t = threadIdx.x;

    if (blockIdx.x < NCONV) {
        // ---- convW: 64 cols in 4 passes of 16 cols (LDS-lean transpose) ----
        #pragma unroll 1
        for (int p = 0; p < 4; ++p) {
            const int c0 = blockIdx.x * 64 + p * 16;
            #pragma unroll
            for (int i = 0; i < 8; ++i) {
                const int e  = t + i * 256;      // 2048 = 128 k x 16 c
                const int kk = e >> 4, c = e & 15;
                const int gc = c0 + c;
                ls[kk][c] = (gc < PV) ? W[(size_t)kk * PV + gc] : 0.f;
            }
            __syncthreads();
            {
                const int c = t >> 4, k0 = (t & 15) * 8;
                f16x8 v;
                #pragma unroll
                for (int j = 0; j < 8; ++j) v[j] = (_Float16)ls[k0 + j][c];
                *reinterpret_cast<f16x8*>(Wt + (size_t)(c0 + c) * PD + k0) = v;
            }
            __syncthreads();
        }
        return;
    }

    // ---- gather: table-major phasing ----
    const int gi  = blockIdx.x - NCONV;
    const int k   = gi / NGB;            // table 0..3
    const int bm0 = (gi % NGB) * 4;

    if (t < 4 * PL) ((int*)sidx)[t] = xe[(size_t)bm0 * PL + t];
    __syncthreads();

    const int w    = t >> 6;             // wave -> bm
    const int lane = t & 63;
    const int h    = lane >> 5;          // row-half
    const int d4   = (lane & 31) * 4;
    const int* si  = sidx[w];
    const float* tab = emb + (size_t)k * TS;

    const float dd0 = (float)(d4 + 0) - 63.0f;
    const float dd1 = (float)(d4 + 1) - 63.0f;
    const float dd2 = (float)(d4 + 2) - 63.0f;
    const float dd3 = (float)(d4 + 3) - 63.0f;

    f32x4 acc = {0.f, 0.f, 0.f, 0.f};
    f32x4 vb[8];

    #pragma unroll
    for (int g = 0; g < 3; ++g) {
        #pragma unroll
        for (int jj = 0; jj < 8; ++jj) {
            const int l = 16 * g + 2 * jj + h;
            vb[jj] = *reinterpret_cast<const f32x4*>(
                tab + (size_t)si[l] * PD + d4);
        }
        #pragma unroll
        for (int jj = 0; jj < 8; ++jj) {
            const int   l  = 16 * g + 2 * jj + h;
            const float fl = PEC * ((float)l - 24.0f);
            const f32x4 wv = {1.0f + fl * dd0, 1.0f + fl * dd1,
                              1.0f + fl * dd2, 1.0f + fl * dd3};
            acc += wv * vb[jj];
        }
    }
    {   // tail rows 48,49
        const int   l  = 48 + h;
        const float fl = PEC * ((float)l - 24.0f);
        const f32x4 v  = *reinterpret_cast<const f32x4*>(
            tab + (size_t)si[l] * PD + d4);
        const f32x4 wv = {1.0f + fl * dd0, 1.0f + fl * dd1,
                          1.0f + fl * dd2, 1.0f + fl * dd3};
        acc += wv * v;
    }

    // combine the two row-halves, lanes 0-31 store 512 B
    f32x4 o;
    o.x = __shfl_down(acc.x, 32);
    o.y = __shfl_down(acc.y, 32);
    o.z = __shfl_down(acc.z, 32);
    o.w = __shfl_down(acc.w, 32);
    if (h == 0) {
        acc += o;
        const int bm = bm0 + w;
        __builtin_nontemporal_store(acc,
            reinterpret_cast<f32x4*>(Mw + ((size_t)k * PBM + bm) * PD + d4));
    }
}

// -------------------------------------------------------------------------
// Kernel 2: per-b u + 3 hops. 256 blocks x 512 threads (unchanged, proven).
// -------------------------------------------------------------------------
__global__ __launch_bounds__(512) void k_hops(const int* __restrict__ xq,
                                              const float* __restrict__ emb,
                                              const float* __restrict__ Mw,
                                              _Float16* __restrict__ uh) {
    const int b = blockIdx.x;
    const int t = threadIdx.x;
    const int g = t >> 7;
    const int d = t & 127;

    __shared__ float us[PD];
    __shared__ float ps[64];
    __shared__ float red[4][PD];
    __shared__ int   sidx[PL];

    if (t < PL) sidx[t] = xq[(size_t)b * PL + t];
    __syncthreads();

    {
        const float dd = (float)d - 63.0f;
        float acc = 0.f;
        for (int l = g; l < PL; l += 4)
            acc += (1.0f + PEC * dd * ((float)l - 24.0f)) *
                   emb[(size_t)sidx[l] * PD + d];
        red[g][d] = acc;
    }
    __syncthreads();
    if (t < PD) us[t] = red[0][t] + red[1][t] + red[2][t] + red[3][t];
    __syncthreads();

    const int lane = t & 63;
    const int wave = t >> 6;

    for (int hop = 0; hop < 3; ++hop) {
        const float* Ma = Mw + ((size_t)hop * PBM + (size_t)b * PM) * PD;
        const float* Mc = Ma + (size_t)PBM * PD;

        for (int m = wave; m < PM; m += 8) {
            const float* row = Ma + (size_t)m * PD;
            float part = row[lane] * us[lane] + row[lane + 64] * us[lane + 64];
            #pragma unroll
            for (int off = 32; off > 0; off >>= 1)
                part += __shfl_down(part, off);
            if (lane == 0) ps[m] = part;
        }
        __syncthreads();

        if (wave == 0) {
            float s = (lane < PM) ? ps[lane] : -INFINITY;
            float mx = s;
            #pragma unroll
            for (int off = 32; off > 0; off >>= 1)
                mx = fmaxf(mx, __shfl_xor(mx, off));
            float e = (lane < PM) ? __expf(s - mx) : 0.f;
            float sm = e;
            #pragma unroll
            for (int off = 32; off > 0; off >>= 1)
                sm += __shfl_xor(sm, off);
            if (lane < PM) ps[lane] = e / sm;
        }
        __syncthreads();

        {
            float o = 0.f;
            for (int m = g; m < PM; m += 4)
                o += ps[m] * Mc[(size_t)m * PD + d];
            red[g][d] = o;
        }
        __syncthreads();
        if (t < PD) us[t] += red[0][t] + red[1][t] + red[2][t] + red[3][t];
        __syncthreads();
    }

    if (t < PD) uh[(size_t)b * PD + t] = (_Float16)us[t];
}

// -------------------------------------------------------------------------
// Kernel 3: GEMM pass — writes exp(v - tile_max) to d_out, (mx,se) to part.
// grid (786, 2), 128 thr (2 waves); each wave: 64 rows x 64 cols.
// -------------------------------------------------------------------------
__global__ __launch_bounds__(128) void k_gemm_exp(const _Float16* __restrict__ uh,
                                                  const _Float16* __restrict__ Wt,
                                                  float* __restrict__ Eout,
                                                  float* __restrict__ part) {
    const int tile    = blockIdx.x;
    const int colBase = tile * 64;
    const int w       = threadIdx.x >> 6;
    const int l       = threadIdx.x & 63;
    const int lrow    = l & 15;
    const int lk      = (l >> 4) * 8;
    const int rowBase = blockIdx.y * 128 + w * 64;

    f32x4 acc[4][4];
    #pragma unroll
    for (int i = 0; i < 4; ++i)
        #pragma unroll
        for (int j = 0; j < 4; ++j)
            acc[i][j] = (f32x4){0.f, 0.f, 0.f, 0.f};

    #pragma unroll
    for (int ks = 0; ks < 4; ++ks) {
        const int k0 = ks * 32 + lk;
        f16x8 a[4], bfr[4];
        #pragma unroll
        for (int mi = 0; mi < 4; ++mi)
            a[mi] = *reinterpret_cast<const f16x8*>(
                uh + (size_t)(rowBase + mi * 16 + lrow) * PD + k0);
        #pragma unroll
        for (int ni = 0; ni < 4; ++ni)
            bfr[ni] = *reinterpret_cast<const f16x8*>(
                Wt + (size_t)(colBase + ni * 16 + lrow) * PD + k0);
        #pragma unroll
        for (int mi = 0; mi < 4; ++mi)
            #pragma unroll
            for (int ni = 0; ni < 4; ++ni)
                acc[mi][ni] = __builtin_amdgcn_mfma_f32_16x16x32_f16(
                    a[mi], bfr[ni], acc[mi][ni], 0, 0, 0);
    }

    // C/D layout: col = lane&15, row = (lane>>4)*4 + reg
    const int rquad = (l >> 4) * 4;
    #pragma unroll
    for (int mi = 0; mi < 4; ++mi) {
        #pragma unroll
        for (int q = 0; q < 4; ++q) {
            const int row = rowBase + mi * 16 + rquad + q;
            float v[4];
            float mx = -INFINITY;
            #pragma unroll
            for (int j = 0; j < 4; ++j) {
                const int col = colBase + j * 16 + lrow;
                v[j] = (col < PV) ? acc[mi][j][q] : -INFINITY;
                mx = fmaxf(mx, v[j]);
            }
            #pragma unroll
            for (int msk = 1; msk < 16; msk <<= 1)
                mx = fmaxf(mx, __shfl_xor(mx, msk));
            float se = 0.f;
            #pragma unroll
            for (int j = 0; j < 4; ++j) {
                const int col = colBase + j * 16 + lrow;
                if (col < PV) {
                    const float e = __expf(v[j] - mx);
                    se += e;
                    __builtin_nontemporal_store(e, Eout + (size_t)row * PV + col);
                }
            }
            #pragma unroll
            for (int msk = 1; msk < 16; msk <<= 1)
                se += __shfl_xor(se, msk);
            if (lrow == 0) {
                part[((size_t)tile * PB + row) * 2 + 0] = mx;
                part[((size_t)tile * PB + row) * 2 + 1] = se;
            }
        }
    }
}

// -------------------------------------------------------------------------
// Kernel 4: merge per-tile partials -> stats[2b]=rowmax, [2b+1]=rowsum.
// -------------------------------------------------------------------------
__global__ __launch_bounds__(64) void k_merge(const float* __restrict__ part,
                                              float* __restrict__ stats) {
    const int b = blockIdx.x;
    const int l = threadIdx.x;
    float M = -INFINITY, S = 0.f;
    for (int t = l; t < NT; t += 64) {
        const float m = part[((size_t)t * PB + b) * 2 + 0];
        const float s = part[((size_t)t * PB + b) * 2 + 1];
        const float nM = fmaxf(M, m);
        S = S * __expf(M - nM) + s * __expf(m - nM);
        M = nM;
    }
    #pragma unroll
    for (int msk = 32; msk > 0; msk >>= 1) {
        const float m2 = __shfl_xor(M, msk);
        const float s2 = __shfl_xor(S, msk);
        const float nM = fmaxf(M, m2);
        S = S * __expf(M - nM) + s2 * __expf(m2 - nM);
        M = nM;
    }
    if (l == 0) { stats[2 * b] = M; stats[2 * b + 1] = S; }
}

// -------------------------------------------------------------------------
// Kernel 5: out[b,c] *= exp(mx_tile - M)/S  (per-row tile scales from LDS).
// 256 blocks x 512 threads.
// -------------------------------------------------------------------------
__global__ __launch_bounds__(512) void k_scale(float* __restrict__ out,
                                               const float* __restrict__ part,
                                               const float* __restrict__ stats) {
    const int b = blockIdx.x;
    const int t = threadIdx.x;
    __shared__ float sc[NT];

    const float M    = stats[2 * b];
    const float rinv = 1.0f / stats[2 * b + 1];
    for (int j = t; j < NT; j += 512)
        sc[j] = __expf(part[((size_t)j * PB + b) * 2 + 0] - M) * rinv;
    __syncthreads();

    float* row = out + (size_t)b * PV;
    const int head = (4 - (b & 3)) & 3;          // align to 16 B
    const int n4   = (PV - head) >> 2;
    const int tail = PV - head - n4 * 4;
    f32x4* vp = reinterpret_cast<f32x4*>(row + head);

    if (t < head) row[t] *= sc[0];
    for (int i = t; i < n4; i += 512) {
        const int c = head + 4 * i;
        f32x4 x = __builtin_nontemporal_load(vp + i);
        if ((c & 63) <= 60) {
            x *= sc[c >> 6];
        } else {
            x.x *= sc[(c + 0) >> 6];
            x.y *= sc[(c + 1) >> 6];
            x.z *= sc[(c + 2) >> 6];
            x.w *= sc[(c + 3) >> 6];
        }
        __builtin_nontemporal_store(x, vp + i);
    }
    if (t < tail) {
        const int ci = head + n4 * 4 + t;
        row[ci] *= sc[ci >> 6];
    }
}

// -------------------------------------------------------------------------
extern "C" void kernel_launch(void* const* d_in, const int* in_sizes, int n_in,
                              void* d_out, int out_size, void* d_ws, size_t ws_size,
                              hipStream_t stream) {
    const int*   x_e = (const int*)d_in[0];    // [B, M, L]
    const int*   x_q = (const int*)d_in[1];    // [B, L]
    const float* emb = (const float*)d_in[2];  // [4, V, D]
    const float* W   = (const float*)d_in[3];  // [D, V]
    float*       out = (float*)d_out;          // [B, V]
    (void)n_in; (void)in_sizes; (void)out_size; (void)ws_size;

    char* p = (char*)d_ws;
    float*    M_ws  = (float*)p;                p += (size_t)4 * PBM * PD * 4;   // 26.2 MB
    _Float16* uh    = (_Float16*)p;             p += (size_t)PB * PD * 2;        // 64 KB
    _Float16* Wt    = (_Float16*)p;             p += (size_t)PVP * PD * 2;       // 12.9 MB
    float*    part  = (float*)p;                p += (size_t)NT * PB * 2 * 4;    // 1.6 MB
    float*    stats = (float*)p;

    k_gather_conv<<<dim3(NCONV + 4 * NGB), dim3(256), 0, stream>>>(
        x_e, emb, W, M_ws, Wt);
    k_hops    <<<dim3(PB),       dim3(512), 0, stream>>>(x_q, emb, M_ws, uh);
    k_gemm_exp<<<dim3(NT, 2),    dim3(128), 0, stream>>>(uh, Wt, out, part);
    k_merge   <<<dim3(PB),       dim3(64),  0, stream>>>(part, stats);
    k_scale   <<<dim3(PB),       dim3(512), 0, stream>>>(out, part, stats);
}

// Round 7
// 284.200 us; speedup vs baseline: 1.2602x; 1.0331x over previous
//
#include <hip/hip_runtime.h>
#include <hip/hip_bf16.h>
#include <hip/hip_fp16.h>
#include <math.h>

// Problem constants (MemN2N): B=256, M=50, L=50, V=50257, D=128, HOPS=3
#define PB   256
#define PM   50
#define PL   50
#define PV   50257
#define PD   128
#define PBM  (PB * PM)              // 12800
#define TS   ((size_t)PV * PD)      // one embedding table, elements
#define PEC  0.000625f              // 4/(D*L) = 4/6400
#define NT   786                    // ceil(PV/64) column tiles
#define PVP  (NT * 64)              // 50304 padded vocab
#define NCONV 786                   // convW blocks at front of sortconv launch
#define NGB2  6400                  // gather blocks per table (2 bm each)

typedef _Float16 f16x8 __attribute__((ext_vector_type(8)));
typedef float    f32x4 __attribute__((ext_vector_type(4)));

// -------------------------------------------------------------------------
// Kernel 0 (fused): blocks 0..785 transpose W -> Wt fp16; blocks 786..3985
// sort each bm's 50 indices ascending (keys idx*64+l) via 64-lane bitonic.
// Indices are shared across all 4 tables -> sort once.
// -------------------------------------------------------------------------
__global__ __launch_bounds__(256) void k_sortconv(const int* __restrict__ xe,
                                                  const float* __restrict__ W,
                                                  unsigned* __restrict__ skey,
                                                  _Float16* __restrict__ Wt) {
    const int t = threadIdx.x;

    if (blockIdx.x < NCONV) {
        __shared__ float ls[PD][17];
        #pragma unroll 1
        for (int p = 0; p < 4; ++p) {
            const int c0 = blockIdx.x * 64 + p * 16;
            #pragma unroll
            for (int i = 0; i < 8; ++i) {
                const int e  = t + i * 256;      // 2048 = 128 k x 16 c
                const int kk = e >> 4, c = e & 15;
                const int gc = c0 + c;
                ls[kk][c] = (gc < PV) ? W[(size_t)kk * PV + gc] : 0.f;
            }
            __syncthreads();
            {
                const int c = t >> 4, k0 = (t & 15) * 8;
                f16x8 v;
                #pragma unroll
                for (int j = 0; j < 8; ++j) v[j] = (_Float16)ls[k0 + j][c];
                *reinterpret_cast<f16x8*>(Wt + (size_t)(c0 + c) * PD + k0) = v;
            }
            __syncthreads();
        }
        return;
    }

    // ---- bitonic sort: one wave per bm ----
    const int wv   = t >> 6;
    const int lane = t & 63;
    const int bm   = (blockIdx.x - NCONV) * 4 + wv;

    unsigned key = 0xFFFFFFFFu;
    if (lane < PL)
        key = ((unsigned)xe[(size_t)bm * PL + lane] << 6) | (unsigned)lane;

    #pragma unroll
    for (int k = 2; k <= 64; k <<= 1) {
        #pragma unroll
        for (int j = k >> 1; j > 0; j >>= 1) {
            const unsigned other = (unsigned)__shfl_xor((int)key, j);
            const bool up      = ((lane & k) == 0);
            const bool keepMin = (((lane & j) == 0) == up);
            const unsigned mn = key < other ? key : other;
            const unsigned mx = key < other ? other : key;
            key = keepMin ? mn : mx;
        }
    }
    if (lane < PL) skey[(size_t)bm * PL + lane] = key;
}

// -------------------------------------------------------------------------
// Kernel 1: sorted-sweep gather. Table-major phasing; within each bm the
// 50 rows are read in ascending vocab order -> co-scheduled blocks share a
// moving ~3.5 MB window (fits per-XCD L2). Round-5 block structure:
// 256 thr = 2 bm x (4 l-subgroups x 32 lanes x float4).
// -------------------------------------------------------------------------
__global__ __launch_bounds__(256) void k_gather(const unsigned* __restrict__ skey,
                                                const float* __restrict__ emb,
                                                float* __restrict__ Mw) {
    const int gi  = blockIdx.x;          // table-major
    const int k   = gi / NGB2;           // table 0..3
    const int bm0 = (gi % NGB2) * 2;
    const int sub = threadIdx.x >> 7;    // bm unit 0/1
    const int tt  = threadIdx.x & 127;
    const int ls  = tt >> 5;             // subgroup 0..3
    const int c   = tt & 31;
    const int d4  = c * 4;
    const int bm  = bm0 + sub;

    __shared__ unsigned sk[2][PL];
    __shared__ f32x4    red[2][3][32];

    if (threadIdx.x < 2 * PL)
        ((unsigned*)sk)[threadIdx.x] = skey[(size_t)bm0 * PL + threadIdx.x];
    __syncthreads();

    const float dd0 = (float)(d4 + 0) - 63.0f;
    const float dd1 = (float)(d4 + 1) - 63.0f;
    const float dd2 = (float)(d4 + 2) - 63.0f;
    const float dd3 = (float)(d4 + 3) - 63.0f;

    float a0 = 0.f, a1 = 0.f, a2 = 0.f, a3 = 0.f;
    const float* tab = emb + (size_t)k * TS;

    #pragma unroll
    for (int i = 0; i < 12; ++i) {
        const unsigned key = sk[sub][ls + 4 * i];     // j ascending per subgroup
        const int   l   = (int)(key & 63u);
        const size_t ix = key >> 6;
        const float fl  = PEC * ((float)l - 24.0f);
        const float4 v  = *reinterpret_cast<const float4*>(tab + ix * PD + d4);
        a0 += (1.0f + fl * dd0) * v.x;
        a1 += (1.0f + fl * dd1) * v.y;
        a2 += (1.0f + fl * dd2) * v.z;
        a3 += (1.0f + fl * dd3) * v.w;
    }
    if (ls < 2) {                        // tail j = 48, 49
        const unsigned key = sk[sub][48 + ls];
        const int   l   = (int)(key & 63u);
        const size_t ix = key >> 6;
        const float fl  = PEC * ((float)l - 24.0f);
        const float4 v  = *reinterpret_cast<const float4*>(tab + ix * PD + d4);
        a0 += (1.0f + fl * dd0) * v.x;
        a1 += (1.0f + fl * dd1) * v.y;
        a2 += (1.0f + fl * dd2) * v.z;
        a3 += (1.0f + fl * dd3) * v.w;
    }

    if (ls > 0) red[sub][ls - 1][c] = (f32x4){a0, a1, a2, a3};
    __syncthreads();
    if (ls == 0) {
        f32x4 s = {a0, a1, a2, a3};
        s += red[sub][0][c];
        s += red[sub][1][c];
        s += red[sub][2][c];
        __builtin_nontemporal_store(s,
            reinterpret_cast<f32x4*>(Mw + ((size_t)k * PBM + bm) * PD + d4));
    }
}

// -------------------------------------------------------------------------
// Kernel 2: per-b u + 3 hops. 256 blocks x 512 threads (unchanged, proven).
// -------------------------------------------------------------------------
__global__ __launch_bounds__(512) void k_hops(const int* __restrict__ xq,
                                              const float* __restrict__ emb,
                                              const float* __restrict__ Mw,
                                              _Float16* __restrict__ uh) {
    const int b = blockIdx.x;
    const int t = threadIdx.x;
    const int g = t >> 7;
    const int d = t & 127;

    __shared__ float us[PD];
    __shared__ float ps[64];
    __shared__ float red[4][PD];
    __shared__ int   sidx[PL];

    if (t < PL) sidx[t] = xq[(size_t)b * PL + t];
    __syncthreads();

    {
        const float dd = (float)d - 63.0f;
        float acc = 0.f;
        for (int l = g; l < PL; l += 4)
            acc += (1.0f + PEC * dd * ((float)l - 24.0f)) *
                   emb[(size_t)sidx[l] * PD + d];
        red[g][d] = acc;
    }
    __syncthreads();
    if (t < PD) us[t] = red[0][t] + red[1][t] + red[2][t] + red[3][t];
    __syncthreads();

    const int lane = t & 63;
    const int wave = t >> 6;

    for (int hop = 0; hop < 3; ++hop) {
        const float* Ma = Mw + ((size_t)hop * PBM + (size_t)b * PM) * PD;
        const float* Mc = Ma + (size_t)PBM * PD;

        for (int m = wave; m < PM; m += 8) {
            const float* row = Ma + (size_t)m * PD;
            float part = row[lane] * us[lane] + row[lane + 64] * us[lane + 64];
            #pragma unroll
            for (int off = 32; off > 0; off >>= 1)
                part += __shfl_down(part, off);
            if (lane == 0) ps[m] = part;
        }
        __syncthreads();

        if (wave == 0) {
            float s = (lane < PM) ? ps[lane] : -INFINITY;
            float mx = s;
            #pragma unroll
            for (int off = 32; off > 0; off >>= 1)
                mx = fmaxf(mx, __shfl_xor(mx, off));
            float e = (lane < PM) ? __expf(s - mx) : 0.f;
            float sm = e;
            #pragma unroll
            for (int off = 32; off > 0; off >>= 1)
                sm += __shfl_xor(sm, off);
            if (lane < PM) ps[lane] = e / sm;
        }
        __syncthreads();

        {
            float o = 0.f;
            for (int m = g; m < PM; m += 4)
                o += ps[m] * Mc[(size_t)m * PD + d];
            red[g][d] = o;
        }
        __syncthreads();
        if (t < PD) us[t] += red[0][t] + red[1][t] + red[2][t] + red[3][t];
        __syncthreads();
    }

    if (t < PD) uh[(size_t)b * PD + t] = (_Float16)us[t];
}

// -------------------------------------------------------------------------
// Kernel 3: GEMM pass — writes exp(v - tile_max) to d_out, (mx,se) to part.
// grid (786, 2), 128 thr (2 waves); each wave: 64 rows x 64 cols.
// -------------------------------------------------------------------------
__global__ __launch_bounds__(128) void k_gemm_exp(const _Float16* __restrict__ uh,
                                                  const _Float16* __restrict__ Wt,
                                                  float* __restrict__ Eout,
                                                  float* __restrict__ part) {
    const int tile    = blockIdx.x;
    const int colBase = tile * 64;
    const int w       = threadIdx.x >> 6;
    const int l       = threadIdx.x & 63;
    const int lrow    = l & 15;
    const int lk      = (l >> 4) * 8;
    const int rowBase = blockIdx.y * 128 + w * 64;

    f32x4 acc[4][4];
    #pragma unroll
    for (int i = 0; i < 4; ++i)
        #pragma unroll
        for (int j = 0; j < 4; ++j)
            acc[i][j] = (f32x4){0.f, 0.f, 0.f, 0.f};

    #pragma unroll
    for (int ks = 0; ks < 4; ++ks) {
        const int k0 = ks * 32 + lk;
        f16x8 a[4], bfr[4];
        #pragma unroll
        for (int mi = 0; mi < 4; ++mi)
            a[mi] = *reinterpret_cast<const f16x8*>(
                uh + (size_t)(rowBase + mi * 16 + lrow) * PD + k0);
        #pragma unroll
        for (int ni = 0; ni < 4; ++ni)
            bfr[ni] = *reinterpret_cast<const f16x8*>(
                Wt + (size_t)(colBase + ni * 16 + lrow) * PD + k0);
        #pragma unroll
        for (int mi = 0; mi < 4; ++mi)
            #pragma unroll
            for (int ni = 0; ni < 4; ++ni)
                acc[mi][ni] = __builtin_amdgcn_mfma_f32_16x16x32_f16(
                    a[mi], bfr[ni], acc[mi][ni], 0, 0, 0);
    }

    // C/D layout: col = lane&15, row = (lane>>4)*4 + reg
    const int rquad = (l >> 4) * 4;
    #pragma unroll
    for (int mi = 0; mi < 4; ++mi) {
        #pragma unroll
        for (int q = 0; q < 4; ++q) {
            const int row = rowBase + mi * 16 + rquad + q;
            float v[4];
            float mx = -INFINITY;
            #pragma unroll
            for (int j = 0; j < 4; ++j) {
                const int col = colBase + j * 16 + lrow;
                v[j] = (col < PV) ? acc[mi][j][q] : -INFINITY;
                mx = fmaxf(mx, v[j]);
            }
            #pragma unroll
            for (int msk = 1; msk < 16; msk <<= 1)
                mx = fmaxf(mx, __shfl_xor(mx, msk));
            float se = 0.f;
            #pragma unroll
            for (int j = 0; j < 4; ++j) {
                const int col = colBase + j * 16 + lrow;
                if (col < PV) {
                    const float e = __expf(v[j] - mx);
                    se += e;
                    __builtin_nontemporal_store(e, Eout + (size_t)row * PV + col);
                }
            }
            #pragma unroll
            for (int msk = 1; msk < 16; msk <<= 1)
                se += __shfl_xor(se, msk);
            if (lrow == 0) {
                part[((size_t)tile * PB + row) * 2 + 0] = mx;
                part[((size_t)tile * PB + row) * 2 + 1] = se;
            }
        }
    }
}

// -------------------------------------------------------------------------
// Kernel 4: merge per-tile partials -> stats[2b]=rowmax, [2b+1]=rowsum.
// -------------------------------------------------------------------------
__global__ __launch_bounds__(64) void k_merge(const float* __restrict__ part,
                                              float* __restrict__ stats) {
    const int b = blockIdx.x;
    const int l = threadIdx.x;
    float M = -INFINITY, S = 0.f;
    for (int t = l; t < NT; t += 64) {
        const float m = part[((size_t)t * PB + b) * 2 + 0];
        const float s = part[((size_t)t * PB + b) * 2 + 1];
        const float nM = fmaxf(M, m);
        S = S * __expf(M - nM) + s * __expf(m - nM);
        M = nM;
    }
    #pragma unroll
    for (int msk = 32; msk > 0; msk >>= 1) {
        const float m2 = __shfl_xor(M, msk);
        const float s2 = __shfl_xor(S, msk);
        const float nM = fmaxf(M, m2);
        S = S * __expf(M - nM) + s2 * __expf(m2 - nM);
        M = nM;
    }
    if (l == 0) { stats[2 * b] = M; stats[2 * b + 1] = S; }
}

// -------------------------------------------------------------------------
// Kernel 5: out[b,c] *= exp(mx_tile - M)/S  (per-row tile scales from LDS).
// -------------------------------------------------------------------------
__global__ __launch_bounds__(512) void k_scale(float* __restrict__ out,
                                               const float* __restrict__ part,
                                               const float* __restrict__ stats) {
    const int b = blockIdx.x;
    const int t = threadIdx.x;
    __shared__ float sc[NT];

    const float M    = stats[2 * b];
    const float rinv = 1.0f / stats[2 * b + 1];
    for (int j = t; j < NT; j += 512)
        sc[j] = __expf(part[((size_t)j * PB + b) * 2 + 0] - M) * rinv;
    __syncthreads();

    float* row = out + (size_t)b * PV;
    const int head = (4 - (b & 3)) & 3;          // align to 16 B
    const int n4   = (PV - head) >> 2;
    const int tail = PV - head - n4 * 4;
    f32x4* vp = reinterpret_cast<f32x4*>(row + head);

    if (t < head) row[t] *= sc[0];
    for (int i = t; i < n4; i += 512) {
        const int c = head + 4 * i;
        f32x4 x = __builtin_nontemporal_load(vp + i);
        if ((c & 63) <= 60) {
            x *= sc[c >> 6];
        } else {
            x.x *= sc[(c + 0) >> 6];
            x.y *= sc[(c + 1) >> 6];
            x.z *= sc[(c + 2) >> 6];
            x.w *= sc[(c + 3) >> 6];
        }
        __builtin_nontemporal_store(x, vp + i);
    }
    if (t < tail) {
        const int ci = head + n4 * 4 + t;
        row[ci] *= sc[ci >> 6];
    }
}

// -------------------------------------------------------------------------
extern "C" void kernel_launch(void* const* d_in, const int* in_sizes, int n_in,
                              void* d_out, int out_size, void* d_ws, size_t ws_size,
                              hipStream_t stream) {
    const int*   x_e = (const int*)d_in[0];    // [B, M, L]
    const int*   x_q = (const int*)d_in[1];    // [B, L]
    const float* emb = (const float*)d_in[2];  // [4, V, D]
    const float* W   = (const float*)d_in[3];  // [D, V]
    float*       out = (float*)d_out;          // [B, V]
    (void)n_in; (void)in_sizes; (void)out_size; (void)ws_size;

    char* p = (char*)d_ws;
    float*    M_ws  = (float*)p;                p += (size_t)4 * PBM * PD * 4;   // 26.2 MB
    _Float16* uh    = (_Float16*)p;             p += (size_t)PB * PD * 2;        // 64 KB
    _Float16* Wt    = (_Float16*)p;             p += (size_t)PVP * PD * 2;       // 12.9 MB
    float*    part  = (float*)p;                p += (size_t)NT * PB * 2 * 4;    // 1.6 MB
    float*    stats = (float*)p;                p += 512 * 4;
    unsigned* skey  = (unsigned*)p;             // 12800*50*4 = 2.56 MB

    k_sortconv<<<dim3(NCONV + PBM / 4), dim3(256), 0, stream>>>(x_e, W, skey, Wt);
    k_gather  <<<dim3(4 * NGB2),        dim3(256), 0, stream>>>(skey, emb, M_ws);
    k_hops    <<<dim3(PB),              dim3(512), 0, stream>>>(x_q, emb, M_ws, uh);
    k_gemm_exp<<<dim3(NT, 2),           dim3(128), 0, stream>>>(uh, Wt, out, part);
    k_merge   <<<dim3(PB),              dim3(64),  0, stream>>>(part, stats);
    k_scale   <<<dim3(PB),              dim3(512), 0, stream>>>(out, part, stats);
}

// Round 8
// 281.062 us; speedup vs baseline: 1.2742x; 1.0112x over previous
//
#include <hip/hip_runtime.h>
#include <hip/hip_bf16.h>
#include <hip/hip_fp16.h>
#include <math.h>

// Problem constants (MemN2N): B=256, M=50, L=50, V=50257, D=128, HOPS=3
#define PB   256
#define PM   50
#define PL   50
#define PV   50257
#define PD   128
#define PBM  (PB * PM)              // 12800
#define TS   ((size_t)PV * PD)      // one embedding table, elements
#define PEC  0.000625f              // 4/(D*L) = 4/6400
#define NT   786                    // ceil(PV/64) column tiles
#define PVP  (NT * 64)              // 50304 padded vocab
#define NCONV 786                   // convW blocks at front of sortconv launch
#define NGB3  6400                  // gather blocks per table (2 bm each)

typedef _Float16 f16x8 __attribute__((ext_vector_type(8)));
typedef float    f32x4 __attribute__((ext_vector_type(4)));

// async global -> LDS, 16 B per lane (dest = uniform base + lane*16)
__device__ __forceinline__ void load_lds16(const float* g, float* l) {
    __builtin_amdgcn_global_load_lds(
        (const __attribute__((address_space(1))) void*)g,
        (__attribute__((address_space(3))) void*)l, 16, 0, 0);
}

// -------------------------------------------------------------------------
// Kernel 0 (fused): blocks 0..785 transpose W -> Wt fp16; rest sort each
// bm's 50 indices ascending (keys idx*64+l) via 64-lane bitonic.
// -------------------------------------------------------------------------
__global__ __launch_bounds__(256) void k_sortconv(const int* __restrict__ xe,
                                                  const float* __restrict__ W,
                                                  unsigned* __restrict__ skey,
                                                  _Float16* __restrict__ Wt) {
    const int t = threadIdx.x;

    if (blockIdx.x < NCONV) {
        __shared__ float ls[PD][17];
        #pragma unroll 1
        for (int p = 0; p < 4; ++p) {
            const int c0 = blockIdx.x * 64 + p * 16;
            #pragma unroll
            for (int i = 0; i < 8; ++i) {
                const int e  = t + i * 256;      // 2048 = 128 k x 16 c
                const int kk = e >> 4, c = e & 15;
                const int gc = c0 + c;
                ls[kk][c] = (gc < PV) ? W[(size_t)kk * PV + gc] : 0.f;
            }
            __syncthreads();
            {
                const int c = t >> 4, k0 = (t & 15) * 8;
                f16x8 v;
                #pragma unroll
                for (int j = 0; j < 8; ++j) v[j] = (_Float16)ls[k0 + j][c];
                *reinterpret_cast<f16x8*>(Wt + (size_t)(c0 + c) * PD + k0) = v;
            }
            __syncthreads();
        }
        return;
    }

    const int wv   = t >> 6;
    const int lane = t & 63;
    const int bm   = (blockIdx.x - NCONV) * 4 + wv;

    unsigned key = 0xFFFFFFFFu;
    if (lane < PL)
        key = ((unsigned)xe[(size_t)bm * PL + lane] << 6) | (unsigned)lane;

    #pragma unroll
    for (int k = 2; k <= 64; k <<= 1) {
        #pragma unroll
        for (int j = k >> 1; j > 0; j >>= 1) {
            const unsigned other = (unsigned)__shfl_xor((int)key, j);
            const bool up      = ((lane & k) == 0);
            const bool keepMin = (((lane & j) == 0) == up);
            const unsigned mn = key < other ? key : other;
            const unsigned mx = key < other ? other : key;
            key = keepMin ? mn : mx;
        }
    }
    if (lane < PL) skey[(size_t)bm * PL + lane] = key;
}

// -------------------------------------------------------------------------
// Kernel 1: deep-MLP gather via global_load_lds. Block = 256 thr (4 waves),
// 2 bm; waves (2s, 2s+1) stage bm s's 50 rows into LDS with 12-13 async
// 1KB loads in flight each, then consume from LDS with PE weights.
// -------------------------------------------------------------------------
__global__ __launch_bounds__(256) void k_gather(const unsigned* __restrict__ skey,
                                                const float* __restrict__ emb,
                                                float* __restrict__ Mw) {
    const int gi  = blockIdx.x;          // table-major
    const int k   = gi / NGB3;           // table 0..3
    const int bm0 = (gi % NGB3) * 2;

    __shared__ unsigned sk[2][PL];
    __shared__ float    rows[2][PL * PD];   // 2 x 25.6 KB
    __shared__ f32x4    xch[2][32];

    const int t    = threadIdx.x;
    const int wid  = t >> 6;
    const int s    = wid >> 1;           // bm sub 0/1
    const int wp   = wid & 1;            // wave parity: 0 -> rows 0-23, 1 -> 24-49
    const int lane = t & 63;
    const int h    = lane >> 5;          // row-in-pair
    const int c    = lane & 31;
    const int d4   = c * 4;

    if (t < 2 * PL) ((unsigned*)sk)[t] = skey[(size_t)bm0 * PL + t];
    __syncthreads();

    const float* tab    = emb + (size_t)k * TS;
    const int    r0     = wp ? 24 : 0;
    const int    NI     = wp ? 13 : 12;
    float*       myrows = &rows[s][0] + r0 * PD;

    // issue all loads back-to-back: 12-13 x 1KB in flight per wave
    for (int jj = 0; jj < NI; ++jj) {
        const int    r  = r0 + 2 * jj + h;
        const size_t ix = (size_t)(sk[s][r] >> 6);
        load_lds16(tab + ix * PD + d4, myrows + jj * 256);
    }
    asm volatile("s_waitcnt vmcnt(0)" ::: "memory");
    __builtin_amdgcn_sched_barrier(0);

    const float dd0 = (float)(d4 + 0) - 63.0f;
    const float dd1 = (float)(d4 + 1) - 63.0f;
    const float dd2 = (float)(d4 + 2) - 63.0f;
    const float dd3 = (float)(d4 + 3) - 63.0f;

    f32x4 acc = {0.f, 0.f, 0.f, 0.f};
    for (int jj = 0; jj < NI; ++jj) {
        const int   r  = r0 + 2 * jj + h;
        const int   l  = (int)(sk[s][r] & 63u);
        const float fl = PEC * ((float)l - 24.0f);
        const f32x4 v  = *reinterpret_cast<const f32x4*>(
            myrows + jj * 256 + h * PD + d4);
        const f32x4 wv = {1.0f + fl * dd0, 1.0f + fl * dd1,
                          1.0f + fl * dd2, 1.0f + fl * dd3};
        acc += wv * v;
    }

    // fold the two row-halves within the wave
    acc.x += __shfl_down(acc.x, 32);
    acc.y += __shfl_down(acc.y, 32);
    acc.z += __shfl_down(acc.z, 32);
    acc.w += __shfl_down(acc.w, 32);

    if (wp == 1 && h == 0) xch[s][c] = acc;
    __syncthreads();
    if (wp == 0 && h == 0) {
        acc += xch[s][c];
        __builtin_nontemporal_store(acc,
            reinterpret_cast<f32x4*>(Mw + ((size_t)k * PBM + bm0 + s) * PD + d4));
    }
}

// -------------------------------------------------------------------------
// Kernel 2: per-b u + 3 hops. 256 blocks x 512 threads (unchanged, proven).
// -------------------------------------------------------------------------
__global__ __launch_bounds__(512) void k_hops(const int* __restrict__ xq,
                                              const float* __restrict__ emb,
                                              const float* __restrict__ Mw,
                                              _Float16* __restrict__ uh) {
    const int b = blockIdx.x;
    const int t = threadIdx.x;
    const int g = t >> 7;
    const int d = t & 127;

    __shared__ float us[PD];
    __shared__ float ps[64];
    __shared__ float red[4][PD];
    __shared__ int   sidx[PL];

    if (t < PL) sidx[t] = xq[(size_t)b * PL + t];
    __syncthreads();

    {
        const float dd = (float)d - 63.0f;
        float acc = 0.f;
        for (int l = g; l < PL; l += 4)
            acc += (1.0f + PEC * dd * ((float)l - 24.0f)) *
                   emb[(size_t)sidx[l] * PD + d];
        red[g][d] = acc;
    }
    __syncthreads();
    if (t < PD) us[t] = red[0][t] + red[1][t] + red[2][t] + red[3][t];
    __syncthreads();

    const int lane = t & 63;
    const int wave = t >> 6;

    for (int hop = 0; hop < 3; ++hop) {
        const float* Ma = Mw + ((size_t)hop * PBM + (size_t)b * PM) * PD;
        const float* Mc = Ma + (size_t)PBM * PD;

        for (int m = wave; m < PM; m += 8) {
            const float* row = Ma + (size_t)m * PD;
            float part = row[lane] * us[lane] + row[lane + 64] * us[lane + 64];
            #pragma unroll
            for (int off = 32; off > 0; off >>= 1)
                part += __shfl_down(part, off);
            if (lane == 0) ps[m] = part;
        }
        __syncthreads();

        if (wave == 0) {
            float s = (lane < PM) ? ps[lane] : -INFINITY;
            float mx = s;
            #pragma unroll
            for (int off = 32; off > 0; off >>= 1)
                mx = fmaxf(mx, __shfl_xor(mx, off));
            float e = (lane < PM) ? __expf(s - mx) : 0.f;
            float sm = e;
            #pragma unroll
            for (int off = 32; off > 0; off >>= 1)
                sm += __shfl_xor(sm, off);
            if (lane < PM) ps[lane] = e / sm;
        }
        __syncthreads();

        {
            float o = 0.f;
            for (int m = g; m < PM; m += 4)
                o += ps[m] * Mc[(size_t)m * PD + d];
            red[g][d] = o;
        }
        __syncthreads();
        if (t < PD) us[t] += red[0][t] + red[1][t] + red[2][t] + red[3][t];
        __syncthreads();
    }

    if (t < PD) uh[(size_t)b * PD + t] = (_Float16)us[t];
}

// -------------------------------------------------------------------------
// Kernel 3: GEMM pass — writes exp(v - tile_max) to d_out, (mx,se) to part.
// grid (786, 2), 128 thr (2 waves); each wave: 64 rows x 64 cols.
// -------------------------------------------------------------------------
__global__ __launch_bounds__(128) void k_gemm_exp(const _Float16* __restrict__ uh,
                                                  const _Float16* __restrict__ Wt,
                                                  float* __restrict__ Eout,
                                                  float* __restrict__ part) {
    const int tile    = blockIdx.x;
    const int colBase = tile * 64;
    const int w       = threadIdx.x >> 6;
    const int l       = threadIdx.x & 63;
    const int lrow    = l & 15;
    const int lk      = (l >> 4) * 8;
    const int rowBase = blockIdx.y * 128 + w * 64;

    f32x4 acc[4][4];
    #pragma unroll
    for (int i = 0; i < 4; ++i)
        #pragma unroll
        for (int j = 0; j < 4; ++j)
            acc[i][j] = (f32x4){0.f, 0.f, 0.f, 0.f};

    #pragma unroll
    for (int ks = 0; ks < 4; ++ks) {
        const int k0 = ks * 32 + lk;
        f16x8 a[4], bfr[4];
        #pragma unroll
        for (int mi = 0; mi < 4; ++mi)
            a[mi] = *reinterpret_cast<const f16x8*>(
                uh + (size_t)(rowBase + mi * 16 + lrow) * PD + k0);
        #pragma unroll
        for (int ni = 0; ni < 4; ++ni)
            bfr[ni] = *reinterpret_cast<const f16x8*>(
                Wt + (size_t)(colBase + ni * 16 + lrow) * PD + k0);
        #pragma unroll
        for (int mi = 0; mi < 4; ++mi)
            #pragma unroll
            for (int ni = 0; ni < 4; ++ni)
                acc[mi][ni] = __builtin_amdgcn_mfma_f32_16x16x32_f16(
                    a[mi], bfr[ni], acc[mi][ni], 0, 0, 0);
    }

    // C/D layout: col = lane&15, row = (lane>>4)*4 + reg
    const int rquad = (l >> 4) * 4;
    #pragma unroll
    for (int mi = 0; mi < 4; ++mi) {
        #pragma unroll
        for (int q = 0; q < 4; ++q) {
            const int row = rowBase + mi * 16 + rquad + q;
            float v[4];
            float mx = -INFINITY;
            #pragma unroll
            for (int j = 0; j < 4; ++j) {
                const int col = colBase + j * 16 + lrow;
                v[j] = (col < PV) ? acc[mi][j][q] : -INFINITY;
                mx = fmaxf(mx, v[j]);
            }
            #pragma unroll
            for (int msk = 1; msk < 16; msk <<= 1)
                mx = fmaxf(mx, __shfl_xor(mx, msk));
            float se = 0.f;
            #pragma unroll
            for (int j = 0; j < 4; ++j) {
                const int col = colBase + j * 16 + lrow;
                if (col < PV) {
                    const float e = __expf(v[j] - mx);
                    se += e;
                    __builtin_nontemporal_store(e, Eout + (size_t)row * PV + col);
                }
            }
            #pragma unroll
            for (int msk = 1; msk < 16; msk <<= 1)
                se += __shfl_xor(se, msk);
            if (lrow == 0) {
                part[((size_t)tile * PB + row) * 2 + 0] = mx;
                part[((size_t)tile * PB + row) * 2 + 1] = se;
            }
        }
    }
}

// -------------------------------------------------------------------------
// Kernel 4: merge per-tile partials -> stats[2b]=rowmax, [2b+1]=rowsum.
// -------------------------------------------------------------------------
__global__ __launch_bounds__(64) void k_merge(const float* __restrict__ part,
                                              float* __restrict__ stats) {
    const int b = blockIdx.x;
    const int l = threadIdx.x;
    float M = -INFINITY, S = 0.f;
    for (int t = l; t < NT; t += 64) {
        const float m = part[((size_t)t * PB + b) * 2 + 0];
        const float s = part[((size_t)t * PB + b) * 2 + 1];
        const float nM = fmaxf(M, m);
        S = S * __expf(M - nM) + s * __expf(m - nM);
        M = nM;
    }
    #pragma unroll
    for (int msk = 32; msk > 0; msk >>= 1) {
        const float m2 = __shfl_xor(M, msk);
        const float s2 = __shfl_xor(S, msk);
        const float nM = fmaxf(M, m2);
        S = S * __expf(M - nM) + s2 * __expf(m2 - nM);
        M = nM;
    }
    if (l == 0) { stats[2 * b] = M; stats[2 * b + 1] = S; }
}

// -------------------------------------------------------------------------
// Kernel 5: out[b,c] *= exp(mx_tile - M)/S  (per-row tile scales from LDS).
// -------------------------------------------------------------------------
__global__ __launch_bounds__(512) void k_scale(float* __restrict__ out,
                                               const float* __restrict__ part,
                                               const float* __restrict__ stats) {
    const int b = blockIdx.x;
    const int t = threadIdx.x;
    __shared__ float sc[NT];

    const float M    = stats[2 * b];
    const float rinv = 1.0f / stats[2 * b + 1];
    for (int j = t; j < NT; j += 512)
        sc[j] = __expf(part[((size_t)j * PB + b) * 2 + 0] - M) * rinv;
    __syncthreads();

    float* row = out + (size_t)b * PV;
    const int head = (4 - (b & 3)) & 3;          // align to 16 B
    const int n4   = (PV - head) >> 2;
    const int tail = PV - head - n4 * 4;
    f32x4* vp = reinterpret_cast<f32x4*>(row + head);

    if (t < head) row[t] *= sc[0];
    for (int i = t; i < n4; i += 512) {
        const int c = head + 4 * i;
        f32x4 x = __builtin_nontemporal_load(vp + i);
        if ((c & 63) <= 60) {
            x *= sc[c >> 6];
        } else {
            x.x *= sc[(c + 0) >> 6];
            x.y *= sc[(c + 1) >> 6];
            x.z *= sc[(c + 2) >> 6];
            x.w *= sc[(c + 3) >> 6];
        }
        __builtin_nontemporal_store(x, vp + i);
    }
    if (t < tail) {
        const int ci = head + n4 * 4 + t;
        row[ci] *= sc[ci >> 6];
    }
}

// -------------------------------------------------------------------------
extern "C" void kernel_launch(void* const* d_in, const int* in_sizes, int n_in,
                              void* d_out, int out_size, void* d_ws, size_t ws_size,
                              hipStream_t stream) {
    const int*   x_e = (const int*)d_in[0];    // [B, M, L]
    const int*   x_q = (const int*)d_in[1];    // [B, L]
    const float* emb = (const float*)d_in[2];  // [4, V, D]
    const float* W   = (const float*)d_in[3];  // [D, V]
    float*       out = (float*)d_out;          // [B, V]
    (void)n_in; (void)in_sizes; (void)out_size; (void)ws_size;

    char* p = (char*)d_ws;
    float*    M_ws  = (float*)p;                p += (size_t)4 * PBM * PD * 4;   // 26.2 MB
    _Float16* uh    = (_Float16*)p;             p += (size_t)PB * PD * 2;        // 64 KB
    _Float16* Wt    = (_Float16*)p;             p += (size_t)PVP * PD * 2;       // 12.9 MB
    float*    part  = (float*)p;                p += (size_t)NT * PB * 2 * 4;    // 1.6 MB
    float*    stats = (float*)p;                p += 512 * 4;
    unsigned* skey  = (unsigned*)p;             // 12800*50*4 = 2.56 MB

    k_sortconv<<<dim3(NCONV + PBM / 4), dim3(256), 0, stream>>>(x_e, W, skey, Wt);
    k_gather  <<<dim3(4 * NGB3),        dim3(256), 0, stream>>>(skey, emb, M_ws);
    k_hops    <<<dim3(PB),              dim3(512), 0, stream>>>(x_q, emb, M_ws, uh);
    k_gemm_exp<<<dim3(NT, 2),           dim3(128), 0, stream>>>(uh, Wt, out, part);
    k_merge   <<<dim3(PB),              dim3(64),  0, stream>>>(part, stats);
    k_scale   <<<dim3(PB),              dim3(512), 0, stream>>>(out, part, stats);
}

// Round 9
// 248.322 us; speedup vs baseline: 1.4422x; 1.1318x over previous
//
#include <hip/hip_runtime.h>
#include <hip/hip_bf16.h>
#include <hip/hip_fp16.h>
#include <math.h>

// Problem constants (MemN2N): B=256, M=50, L=50, V=50257, D=128, HOPS=3
#define PB   256
#define PM   50
#define PL   50
#define PV   50257
#define PD   128
#define PBM  (PB * PM)              // 12800
#define TS   ((size_t)PV * PD)      // one embedding table, elements
#define PEC  0.000625f              // 4/(D*L) = 4/6400
#define NT   786                    // ceil(PV/64) column tiles
#define PVP  (NT * 64)              // 50304 padded vocab
#define NCONV 786                   // convW blocks at front of fused launch
#define NGB2  6400                  // gather blocks per table (2 bm each)

typedef _Float16 f16x8 __attribute__((ext_vector_type(8)));
typedef float    f32x4 __attribute__((ext_vector_type(4)));

// -------------------------------------------------------------------------
// Kernel 1 (fused): blocks 0..785 transpose W -> Wt fp16 (vectorized loads);
// blocks 786.. table-phased gather (round-5 proven structure, raw xe, no
// sort — sorting measured as worthless). Conv traffic overlaps the gather's
// service-path-bound phase instead of running serially.
// -------------------------------------------------------------------------
__global__ __launch_bounds__(256) void k_gatherconv(const int* __restrict__ xe,
                                                    const float* __restrict__ emb,
                                                    const float* __restrict__ W,
                                                    float* __restrict__ Mw,
                                                    _Float16* __restrict__ Wt) {
    const int t = threadIdx.x;

    if (blockIdx.x < NCONV) {
        // ---- convW: 64 cols in 4 passes of 16 cols, f32x4 global loads ----
        __shared__ float ls[PD][20];          // stride 80B: 16B-aligned rows
        const bool edge = (blockIdx.x == NCONV - 1);
        #pragma unroll 1
        for (int p = 0; p < 4; ++p) {
            const int c0 = blockIdx.x * 64 + p * 16;
            #pragma unroll
            for (int i = 0; i < 2; ++i) {
                const int e  = t + i * 256;   // 512 chunks = 128 rows x 4
                const int kk = e >> 2, c4 = (e & 3) * 4;
                const int gc = c0 + c4;
                f32x4 v;
                if (!edge || gc + 3 < PV) {
                    v = *reinterpret_cast<const f32x4*>(W + (size_t)kk * PV + gc);
                } else {
                    v.x = (gc + 0 < PV) ? W[(size_t)kk * PV + gc + 0] : 0.f;
                    v.y = (gc + 1 < PV) ? W[(size_t)kk * PV + gc + 1] : 0.f;
                    v.z = (gc + 2 < PV) ? W[(size_t)kk * PV + gc + 2] : 0.f;
                    v.w = (gc + 3 < PV) ? W[(size_t)kk * PV + gc + 3] : 0.f;
                }
                *reinterpret_cast<f32x4*>(&ls[kk][c4]) = v;
            }
            __syncthreads();
            {
                const int c = t >> 4, k0 = (t & 15) * 8;
                f16x8 v;
                #pragma unroll
                for (int j = 0; j < 8; ++j) v[j] = (_Float16)ls[k0 + j][c];
                *reinterpret_cast<f16x8*>(Wt + (size_t)(c0 + c) * PD + k0) = v;
            }
            __syncthreads();
        }
        return;
    }

    // ---- gather: table-major phasing, 2 bm x (4 subgroups x 32 lanes) ----
    const int gi  = blockIdx.x - NCONV;
    const int k   = gi / NGB2;           // table 0..3
    const int bm0 = (gi % NGB2) * 2;
    const int sub = t >> 7;              // bm unit 0/1
    const int tt  = t & 127;
    const int sg  = tt >> 5;             // l subgroup 0..3
    const int c   = tt & 31;
    const int d4  = c * 4;
    const int bm  = bm0 + sub;

    __shared__ int   sidx[2][PL];
    __shared__ f32x4 red[2][3][32];

    if (t < 2 * PL) ((int*)sidx)[t] = xe[(size_t)bm0 * PL + t];
    __syncthreads();

    const float dd0 = (float)(d4 + 0) - 63.0f;
    const float dd1 = (float)(d4 + 1) - 63.0f;
    const float dd2 = (float)(d4 + 2) - 63.0f;
    const float dd3 = (float)(d4 + 3) - 63.0f;

    float a0 = 0.f, a1 = 0.f, a2 = 0.f, a3 = 0.f;
    const float* tab = emb + (size_t)k * TS;

    #pragma unroll
    for (int i = 0; i < 12; ++i) {
        const int   l  = sg + 4 * i;
        const float fl = PEC * ((float)l - 24.0f);
        const float4 v = *reinterpret_cast<const float4*>(
            tab + (size_t)sidx[sub][l] * PD + d4);
        a0 += (1.0f + fl * dd0) * v.x;
        a1 += (1.0f + fl * dd1) * v.y;
        a2 += (1.0f + fl * dd2) * v.z;
        a3 += (1.0f + fl * dd3) * v.w;
    }
    if (sg < 2) {                        // tail l = 48, 49
        const int   l  = 48 + sg;
        const float fl = PEC * ((float)l - 24.0f);
        const float4 v = *reinterpret_cast<const float4*>(
            tab + (size_t)sidx[sub][l] * PD + d4);
        a0 += (1.0f + fl * dd0) * v.x;
        a1 += (1.0f + fl * dd1) * v.y;
        a2 += (1.0f + fl * dd2) * v.z;
        a3 += (1.0f + fl * dd3) * v.w;
    }

    if (sg > 0) red[sub][sg - 1][c] = (f32x4){a0, a1, a2, a3};
    __syncthreads();
    if (sg == 0) {
        f32x4 s = {a0, a1, a2, a3};
        s += red[sub][0][c];
        s += red[sub][1][c];
        s += red[sub][2][c];
        __builtin_nontemporal_store(s,
            reinterpret_cast<f32x4*>(Mw + ((size_t)k * PBM + bm) * PD + d4));
    }
}

// -------------------------------------------------------------------------
// Kernel 2: per-b u + 3 hops. 256 blocks x 512 threads (unchanged, proven).
// -------------------------------------------------------------------------
__global__ __launch_bounds__(512) void k_hops(const int* __restrict__ xq,
                                              const float* __restrict__ emb,
                                              const float* __restrict__ Mw,
                                              _Float16* __restrict__ uh) {
    const int b = blockIdx.x;
    const int t = threadIdx.x;
    const int g = t >> 7;
    const int d = t & 127;

    __shared__ float us[PD];
    __shared__ float ps[64];
    __shared__ float red[4][PD];
    __shared__ int   sidx[PL];

    if (t < PL) sidx[t] = xq[(size_t)b * PL + t];
    __syncthreads();

    {
        const float dd = (float)d - 63.0f;
        float acc = 0.f;
        for (int l = g; l < PL; l += 4)
            acc += (1.0f + PEC * dd * ((float)l - 24.0f)) *
                   emb[(size_t)sidx[l] * PD + d];
        red[g][d] = acc;
    }
    __syncthreads();
    if (t < PD) us[t] = red[0][t] + red[1][t] + red[2][t] + red[3][t];
    __syncthreads();

    const int lane = t & 63;
    const int wave = t >> 6;

    for (int hop = 0; hop < 3; ++hop) {
        const float* Ma = Mw + ((size_t)hop * PBM + (size_t)b * PM) * PD;
        const float* Mc = Ma + (size_t)PBM * PD;

        for (int m = wave; m < PM; m += 8) {
            const float* row = Ma + (size_t)m * PD;
            float part = row[lane] * us[lane] + row[lane + 64] * us[lane + 64];
            #pragma unroll
            for (int off = 32; off > 0; off >>= 1)
                part += __shfl_down(part, off);
            if (lane == 0) ps[m] = part;
        }
        __syncthreads();

        if (wave == 0) {
            float s = (lane < PM) ? ps[lane] : -INFINITY;
            float mx = s;
            #pragma unroll
            for (int off = 32; off > 0; off >>= 1)
                mx = fmaxf(mx, __shfl_xor(mx, off));
            float e = (lane < PM) ? __expf(s - mx) : 0.f;
            float sm = e;
            #pragma unroll
            for (int off = 32; off > 0; off >>= 1)
                sm += __shfl_xor(sm, off);
            if (lane < PM) ps[lane] = e / sm;
        }
        __syncthreads();

        {
            float o = 0.f;
            for (int m = g; m < PM; m += 4)
                o += ps[m] * Mc[(size_t)m * PD + d];
            red[g][d] = o;
        }
        __syncthreads();
        if (t < PD) us[t] += red[0][t] + red[1][t] + red[2][t] + red[3][t];
        __syncthreads();
    }

    if (t < PD) uh[(size_t)b * PD + t] = (_Float16)us[t];
}

// -------------------------------------------------------------------------
// Kernel 3: GEMM pass — E = exp(v - tile_max) in fp16 (LDS-staged coalesced
// f16x8 stores, PVP-padded so no col guard), (mx,se) to part.
// grid (786, 2), 128 thr (2 waves); each wave: 64 rows x 64 cols.
// -------------------------------------------------------------------------
__global__ __launch_bounds__(128) void k_gemm_exp(const _Float16* __restrict__ uh,
                                                  const _Float16* __restrict__ Wt,
                                                  _Float16* __restrict__ Eh,
                                                  float* __restrict__ part) {
    const int tile    = blockIdx.x;
    const int colBase = tile * 64;
    const int w       = threadIdx.x >> 6;
    const int l       = threadIdx.x & 63;
    const int lrow    = l & 15;
    const int lk      = (l >> 4) * 8;
    const int rb0     = blockIdx.y * 128;
    const int rowBase = rb0 + w * 64;

    __shared__ _Float16 es[128][72];     // stride 144B: 16B-aligned, 2-way banks

    f32x4 acc[4][4];
    #pragma unroll
    for (int i = 0; i < 4; ++i)
        #pragma unroll
        for (int j = 0; j < 4; ++j)
            acc[i][j] = (f32x4){0.f, 0.f, 0.f, 0.f};

    #pragma unroll
    for (int ks = 0; ks < 4; ++ks) {
        const int k0 = ks * 32 + lk;
        f16x8 a[4], bfr[4];
        #pragma unroll
        for (int mi = 0; mi < 4; ++mi)
            a[mi] = *reinterpret_cast<const f16x8*>(
                uh + (size_t)(rowBase + mi * 16 + lrow) * PD + k0);
        #pragma unroll
        for (int ni = 0; ni < 4; ++ni)
            bfr[ni] = *reinterpret_cast<const f16x8*>(
                Wt + (size_t)(colBase + ni * 16 + lrow) * PD + k0);
        #pragma unroll
        for (int mi = 0; mi < 4; ++mi)
            #pragma unroll
            for (int ni = 0; ni < 4; ++ni)
                acc[mi][ni] = __builtin_amdgcn_mfma_f32_16x16x32_f16(
                    a[mi], bfr[ni], acc[mi][ni], 0, 0, 0);
    }

    // C/D layout: col = lane&15, row = (lane>>4)*4 + reg
    const int rquad = (l >> 4) * 4;
    #pragma unroll
    for (int mi = 0; mi < 4; ++mi) {
        #pragma unroll
        for (int q = 0; q < 4; ++q) {
            const int row   = rowBase + mi * 16 + rquad + q;
            const int row_l = row - rb0;
            float v[4];
            float mx = -INFINITY;
            #pragma unroll
            for (int j = 0; j < 4; ++j) {
                const int col = colBase + j * 16 + lrow;
                v[j] = (col < PV) ? acc[mi][j][q] : -INFINITY;
                mx = fmaxf(mx, v[j]);
            }
            #pragma unroll
            for (int msk = 1; msk < 16; msk <<= 1)
                mx = fmaxf(mx, __shfl_xor(mx, msk));
            float se = 0.f;
            #pragma unroll
            for (int j = 0; j < 4; ++j) {
                const float e = __expf(v[j] - mx);   // pad cols -> exp(-inf)=0
                se += e;
                es[row_l][j * 16 + lrow] = (_Float16)e;
            }
            #pragma unroll
            for (int msk = 1; msk < 16; msk <<= 1)
                se += __shfl_xor(se, msk);
            if (lrow == 0) {
                part[((size_t)tile * PB + row) * 2 + 0] = mx;
                part[((size_t)tile * PB + row) * 2 + 1] = se;
            }
        }
    }
    __syncthreads();

    // coalesced writeout: 1024 f16x8 chunks, 128 thr x 8
    #pragma unroll
    for (int i = 0; i < 8; ++i) {
        const int ch    = threadIdx.x + i * 128;
        const int row_l = ch >> 3, cq = ch & 7;
        const f16x8 v = *reinterpret_cast<const f16x8*>(&es[row_l][cq * 8]);
        __builtin_nontemporal_store(v, reinterpret_cast<f16x8*>(
            Eh + (size_t)(rb0 + row_l) * PVP + colBase + cq * 8));
    }
}

// -------------------------------------------------------------------------
// Kernel 4: fused merge + scale. Per block b: online-merge 786 partials to
// (M,S), build per-tile scales in LDS, stream E fp16 -> out fp32.
// -------------------------------------------------------------------------
__global__ __launch_bounds__(512) void k_scale(const _Float16* __restrict__ Eh,
                                               const float* __restrict__ part,
                                               float* __restrict__ out) {
    const int b = blockIdx.x;
    const int t = threadIdx.x;
    __shared__ float sc[NT];
    __shared__ float wm[8], ws[8];

    float M = -INFINITY, S = 0.f;
    for (int tile = t; tile < NT; tile += 512) {
        const float m = part[((size_t)tile * PB + b) * 2 + 0];
        const float s = part[((size_t)tile * PB + b) * 2 + 1];
        const float nM = fmaxf(M, m);
        S = S * __expf(M - nM) + s * __expf(m - nM);
        M = nM;
    }
    #pragma unroll
    for (int off = 32; off > 0; off >>= 1) {
        const float m2 = __shfl_xor(M, off);
        const float s2 = __shfl_xor(S, off);
        const float nM = fmaxf(M, m2);
        S = S * __expf(M - nM) + s2 * __expf(m2 - nM);
        M = nM;
    }
    if ((t & 63) == 0) { wm[t >> 6] = M; ws[t >> 6] = S; }
    __syncthreads();
    M = -INFINITY; S = 0.f;
    #pragma unroll
    for (int i = 0; i < 8; ++i) {
        const float m = wm[i], s = ws[i];
        const float nM = fmaxf(M, m);
        S = S * __expf(M - nM) + s * __expf(m - nM);
        M = nM;
    }
    const float rinv = 1.0f / S;

    for (int tile = t; tile < NT; tile += 512)
        sc[tile] = __expf(part[((size_t)tile * PB + b) * 2 + 0] - M) * rinv;
    __syncthreads();

    const _Float16* erow = Eh + (size_t)b * PVP;
    float*          orow = out + (size_t)b * PV;
    for (int i = t; i < PV; i += 512)
        orow[i] = (float)erow[i] * sc[i >> 6];
}

// -------------------------------------------------------------------------
extern "C" void kernel_launch(void* const* d_in, const int* in_sizes, int n_in,
                              void* d_out, int out_size, void* d_ws, size_t ws_size,
                              hipStream_t stream) {
    const int*   x_e = (const int*)d_in[0];    // [B, M, L]
    const int*   x_q = (const int*)d_in[1];    // [B, L]
    const float* emb = (const float*)d_in[2];  // [4, V, D]
    const float* W   = (const float*)d_in[3];  // [D, V]
    float*       out = (float*)d_out;          // [B, V]
    (void)n_in; (void)in_sizes; (void)out_size; (void)ws_size;

    char* p = (char*)d_ws;
    float*    M_ws = (float*)p;                p += (size_t)4 * PBM * PD * 4;   // 26.2 MB
    _Float16* uh   = (_Float16*)p;             p += (size_t)PB * PD * 2;        // 64 KB
    _Float16* Wt   = (_Float16*)p;             p += (size_t)PVP * PD * 2;       // 12.9 MB
    float*    part = (float*)p;                p += (size_t)NT * PB * 2 * 4;    // 1.6 MB
    _Float16* Eh   = (_Float16*)p;             // 256*50304*2 = 25.8 MB

    k_gatherconv<<<dim3(NCONV + 4 * NGB2), dim3(256), 0, stream>>>(
        x_e, emb, W, M_ws, Wt);
    k_hops    <<<dim3(PB),    dim3(512), 0, stream>>>(x_q, emb, M_ws, uh);
    k_gemm_exp<<<dim3(NT, 2), dim3(128), 0, stream>>>(uh, Wt, Eh, part);
    k_scale   <<<dim3(PB),    dim3(512), 0, stream>>>(Eh, part, out);
}

// Round 10
// 234.406 us; speedup vs baseline: 1.5278x; 1.0594x over previous
//
#include <hip/hip_runtime.h>
#include <hip/hip_bf16.h>
#include <hip/hip_fp16.h>
#include <math.h>

// Problem constants (MemN2N): B=256, M=50, L=50, V=50257, D=128, HOPS=3
#define PB   256
#define PM   50
#define PL   50
#define PV   50257
#define PD   128
#define PBM  (PB * PM)              // 12800
#define TS   ((size_t)PV * PD)      // one embedding table, elements
#define PEC  0.000625f              // 4/(D*L) = 4/6400
#define NT   786                    // ceil(PV/64) column tiles
#define PVP  (NT * 64)              // 50304 padded vocab
#define NCONV 786                   // convW blocks at front of fused launch
#define NGB2  6400                  // gather blocks per table (2 bm each)

typedef _Float16 f16x8 __attribute__((ext_vector_type(8)));
typedef float    f32x4 __attribute__((ext_vector_type(4)));

// -------------------------------------------------------------------------
// Kernel 1 (fused): blocks 0..785 transpose W -> Wt fp16; blocks 786..
// table-phased gather (proven round-5 structure). Conv traffic overlaps the
// gather's service-path-bound phase.
// -------------------------------------------------------------------------
__global__ __launch_bounds__(256) void k_gatherconv(const int* __restrict__ xe,
                                                    const float* __restrict__ emb,
                                                    const float* __restrict__ W,
                                                    float* __restrict__ Mw,
                                                    _Float16* __restrict__ Wt) {
    const int t = threadIdx.x;

    if (blockIdx.x < NCONV) {
        // ---- convW: 64 cols in 4 passes of 16 cols, f32x4 global loads ----
        __shared__ float ls[PD][20];          // stride 80B: 16B-aligned rows
        const bool edge = (blockIdx.x == NCONV - 1);
        #pragma unroll 1
        for (int p = 0; p < 4; ++p) {
            const int c0 = blockIdx.x * 64 + p * 16;
            #pragma unroll
            for (int i = 0; i < 2; ++i) {
                const int e  = t + i * 256;   // 512 chunks = 128 rows x 4
                const int kk = e >> 2, c4 = (e & 3) * 4;
                const int gc = c0 + c4;
                f32x4 v;
                if (!edge || gc + 3 < PV) {
                    v = *reinterpret_cast<const f32x4*>(W + (size_t)kk * PV + gc);
                } else {
                    v.x = (gc + 0 < PV) ? W[(size_t)kk * PV + gc + 0] : 0.f;
                    v.y = (gc + 1 < PV) ? W[(size_t)kk * PV + gc + 1] : 0.f;
                    v.z = (gc + 2 < PV) ? W[(size_t)kk * PV + gc + 2] : 0.f;
                    v.w = (gc + 3 < PV) ? W[(size_t)kk * PV + gc + 3] : 0.f;
                }
                *reinterpret_cast<f32x4*>(&ls[kk][c4]) = v;
            }
            __syncthreads();
            {
                const int c = t >> 4, k0 = (t & 15) * 8;
                f16x8 v;
                #pragma unroll
                for (int j = 0; j < 8; ++j) v[j] = (_Float16)ls[k0 + j][c];
                *reinterpret_cast<f16x8*>(Wt + (size_t)(c0 + c) * PD + k0) = v;
            }
            __syncthreads();
        }
        return;
    }

    // ---- gather: table-major phasing, 2 bm x (4 subgroups x 32 lanes) ----
    const int gi  = blockIdx.x - NCONV;
    const int k   = gi / NGB2;           // table 0..3
    const int bm0 = (gi % NGB2) * 2;
    const int sub = t >> 7;              // bm unit 0/1
    const int tt  = t & 127;
    const int sg  = tt >> 5;             // l subgroup 0..3
    const int c   = tt & 31;
    const int d4  = c * 4;
    const int bm  = bm0 + sub;

    __shared__ int   sidx[2][PL];
    __shared__ f32x4 red[2][3][32];

    if (t < 2 * PL) ((int*)sidx)[t] = xe[(size_t)bm0 * PL + t];
    __syncthreads();

    const float dd0 = (float)(d4 + 0) - 63.0f;
    const float dd1 = (float)(d4 + 1) - 63.0f;
    const float dd2 = (float)(d4 + 2) - 63.0f;
    const float dd3 = (float)(d4 + 3) - 63.0f;

    float a0 = 0.f, a1 = 0.f, a2 = 0.f, a3 = 0.f;
    const float* tab = emb + (size_t)k * TS;

    #pragma unroll
    for (int i = 0; i < 12; ++i) {
        const int   l  = sg + 4 * i;
        const float fl = PEC * ((float)l - 24.0f);
        const float4 v = *reinterpret_cast<const float4*>(
            tab + (size_t)sidx[sub][l] * PD + d4);
        a0 += (1.0f + fl * dd0) * v.x;
        a1 += (1.0f + fl * dd1) * v.y;
        a2 += (1.0f + fl * dd2) * v.z;
        a3 += (1.0f + fl * dd3) * v.w;
    }
    if (sg < 2) {                        // tail l = 48, 49
        const int   l  = 48 + sg;
        const float fl = PEC * ((float)l - 24.0f);
        const float4 v = *reinterpret_cast<const float4*>(
            tab + (size_t)sidx[sub][l] * PD + d4);
        a0 += (1.0f + fl * dd0) * v.x;
        a1 += (1.0f + fl * dd1) * v.y;
        a2 += (1.0f + fl * dd2) * v.z;
        a3 += (1.0f + fl * dd3) * v.w;
    }

    if (sg > 0) red[sub][sg - 1][c] = (f32x4){a0, a1, a2, a3};
    __syncthreads();
    if (sg == 0) {
        f32x4 s = {a0, a1, a2, a3};
        s += red[sub][0][c];
        s += red[sub][1][c];
        s += red[sub][2][c];
        // plain store: keep M in L2/L3 for k_hops (nt hint removed — the
        // "protect tables" theory was disproved by warm-replay FETCH data)
        *reinterpret_cast<f32x4*>(Mw + ((size_t)k * PBM + bm) * PD + d4) = s;
    }
}

// -------------------------------------------------------------------------
// Kernel 2: per-b u + 3 hops. 256 blocks x 1024 threads (16 waves): more
// concurrent memory streams in the only 1-block/CU kernel.
// -------------------------------------------------------------------------
__global__ __launch_bounds__(1024) void k_hops(const int* __restrict__ xq,
                                               const float* __restrict__ emb,
                                               const float* __restrict__ Mw,
                                               _Float16* __restrict__ uh) {
    const int b = blockIdx.x;
    const int t = threadIdx.x;
    const int g = t >> 7;        // group 0..7
    const int d = t & 127;

    __shared__ float us[PD];
    __shared__ float ps[64];
    __shared__ float red[8][PD];
    __shared__ int   sidx[PL];

    if (t < PL) sidx[t] = xq[(size_t)b * PL + t];
    __syncthreads();

    {
        const float dd = (float)d - 63.0f;
        float acc = 0.f;
        for (int l = g; l < PL; l += 8)
            acc += (1.0f + PEC * dd * ((float)l - 24.0f)) *
                   emb[(size_t)sidx[l] * PD + d];
        red[g][d] = acc;
    }
    __syncthreads();
    if (t < PD) {
        float s = red[0][t];
        #pragma unroll
        for (int i = 1; i < 8; ++i) s += red[i][t];
        us[t] = s;
    }
    __syncthreads();

    const int lane = t & 63;
    const int wave = t >> 6;     // 0..15

    for (int hop = 0; hop < 3; ++hop) {
        const float* Ma = Mw + ((size_t)hop * PBM + (size_t)b * PM) * PD;
        const float* Mc = Ma + (size_t)PBM * PD;

        for (int m = wave; m < PM; m += 16) {
            const float* row = Ma + (size_t)m * PD;
            float part = row[lane] * us[lane] + row[lane + 64] * us[lane + 64];
            #pragma unroll
            for (int off = 32; off > 0; off >>= 1)
                part += __shfl_down(part, off);
            if (lane == 0) ps[m] = part;
        }
        __syncthreads();

        if (wave == 0) {
            float s = (lane < PM) ? ps[lane] : -INFINITY;
            float mx = s;
            #pragma unroll
            for (int off = 32; off > 0; off >>= 1)
                mx = fmaxf(mx, __shfl_xor(mx, off));
            float e = (lane < PM) ? __expf(s - mx) : 0.f;
            float sm = e;
            #pragma unroll
            for (int off = 32; off > 0; off >>= 1)
                sm += __shfl_xor(sm, off);
            if (lane < PM) ps[lane] = e / sm;
        }
        __syncthreads();

        {
            float o = 0.f;
            for (int m = g; m < PM; m += 8)
                o += ps[m] * Mc[(size_t)m * PD + d];
            red[g][d] = o;
        }
        __syncthreads();
        if (t < PD) {
            float s = red[0][t];
            #pragma unroll
            for (int i = 1; i < 8; ++i) s += red[i][t];
            us[t] += s;
        }
        __syncthreads();
    }

    if (t < PD) uh[(size_t)b * PD + t] = (_Float16)us[t];
}

// -------------------------------------------------------------------------
// Kernel 3: GEMM pass — E = exp(v - tile_max) fp16 (LDS-staged, coalesced
// f16x8 stores), (mx,se) to part. grid (786,2), 128 thr.
// -------------------------------------------------------------------------
__global__ __launch_bounds__(128) void k_gemm_exp(const _Float16* __restrict__ uh,
                                                  const _Float16* __restrict__ Wt,
                                                  _Float16* __restrict__ Eh,
                                                  float* __restrict__ part) {
    const int tile    = blockIdx.x;
    const int colBase = tile * 64;
    const int w       = threadIdx.x >> 6;
    const int l       = threadIdx.x & 63;
    const int lrow    = l & 15;
    const int lk      = (l >> 4) * 8;
    const int rb0     = blockIdx.y * 128;
    const int rowBase = rb0 + w * 64;

    __shared__ _Float16 es[128][72];     // stride 144B

    f32x4 acc[4][4];
    #pragma unroll
    for (int i = 0; i < 4; ++i)
        #pragma unroll
        for (int j = 0; j < 4; ++j)
            acc[i][j] = (f32x4){0.f, 0.f, 0.f, 0.f};

    #pragma unroll
    for (int ks = 0; ks < 4; ++ks) {
        const int k0 = ks * 32 + lk;
        f16x8 a[4], bfr[4];
        #pragma unroll
        for (int mi = 0; mi < 4; ++mi)
            a[mi] = *reinterpret_cast<const f16x8*>(
                uh + (size_t)(rowBase + mi * 16 + lrow) * PD + k0);
        #pragma unroll
        for (int ni = 0; ni < 4; ++ni)
            bfr[ni] = *reinterpret_cast<const f16x8*>(
                Wt + (size_t)(colBase + ni * 16 + lrow) * PD + k0);
        #pragma unroll
        for (int mi = 0; mi < 4; ++mi)
            #pragma unroll
            for (int ni = 0; ni < 4; ++ni)
                acc[mi][ni] = __builtin_amdgcn_mfma_f32_16x16x32_f16(
                    a[mi], bfr[ni], acc[mi][ni], 0, 0, 0);
    }

    // C/D layout: col = lane&15, row = (lane>>4)*4 + reg
    const int rquad = (l >> 4) * 4;
    #pragma unroll
    for (int mi = 0; mi < 4; ++mi) {
        #pragma unroll
        for (int q = 0; q < 4; ++q) {
            const int row   = rowBase + mi * 16 + rquad + q;
            const int row_l = row - rb0;
            float v[4];
            float mx = -INFINITY;
            #pragma unroll
            for (int j = 0; j < 4; ++j) {
                const int col = colBase + j * 16 + lrow;
                v[j] = (col < PV) ? acc[mi][j][q] : -INFINITY;
                mx = fmaxf(mx, v[j]);
            }
            #pragma unroll
            for (int msk = 1; msk < 16; msk <<= 1)
                mx = fmaxf(mx, __shfl_xor(mx, msk));
            float se = 0.f;
            #pragma unroll
            for (int j = 0; j < 4; ++j) {
                const float e = __expf(v[j] - mx);   // pad cols: exp(-inf)=0
                se += e;
                es[row_l][j * 16 + lrow] = (_Float16)e;
            }
            #pragma unroll
            for (int msk = 1; msk < 16; msk <<= 1)
                se += __shfl_xor(se, msk);
            if (lrow == 0) {
                part[((size_t)tile * PB + row) * 2 + 0] = mx;
                part[((size_t)tile * PB + row) * 2 + 1] = se;
            }
        }
    }
    __syncthreads();

    // coalesced writeout (plain stores: keep E in L2/L3 for k_scale)
    #pragma unroll
    for (int i = 0; i < 8; ++i) {
        const int ch    = threadIdx.x + i * 128;
        const int row_l = ch >> 3, cq = ch & 7;
        const f16x8 v = *reinterpret_cast<const f16x8*>(&es[row_l][cq * 8]);
        *reinterpret_cast<f16x8*>(
            Eh + (size_t)(rb0 + row_l) * PVP + colBase + cq * 8) = v;
    }
}

// -------------------------------------------------------------------------
// Kernel 4: fused merge + scale. Per block b: online-merge 786 partials,
// per-tile scales in LDS, stream E fp16 (paired f16x2 loads) -> out fp32.
// -------------------------------------------------------------------------
__global__ __launch_bounds__(512) void k_scale(const _Float16* __restrict__ Eh,
                                               const float* __restrict__ part,
                                               float* __restrict__ out) {
    const int b = blockIdx.x;
    const int t = threadIdx.x;
    __shared__ float sc[NT];
    __shared__ float wm[8], ws[8];

    float M = -INFINITY, S = 0.f;
    for (int tile = t; tile < NT; tile += 512) {
        const float m = part[((size_t)tile * PB + b) * 2 + 0];
        const float s = part[((size_t)tile * PB + b) * 2 + 1];
        const float nM = fmaxf(M, m);
        S = S * __expf(M - nM) + s * __expf(m - nM);
        M = nM;
    }
    #pragma unroll
    for (int off = 32; off > 0; off >>= 1) {
        const float m2 = __shfl_xor(M, off);
        const float s2 = __shfl_xor(S, off);
        const float nM = fmaxf(M, m2);
        S = S * __expf(M - nM) + s2 * __expf(m2 - nM);
        M = nM;
    }
    if ((t & 63) == 0) { wm[t >> 6] = M; ws[t >> 6] = S; }
    __syncthreads();
    M = -INFINITY; S = 0.f;
    #pragma unroll
    for (int i = 0; i < 8; ++i) {
        const float m = wm[i], s = ws[i];
        const float nM = fmaxf(M, m);
        S = S * __expf(M - nM) + s * __expf(m - nM);
        M = nM;
    }
    const float rinv = 1.0f / S;

    for (int tile = t; tile < NT; tile += 512)
        sc[tile] = __expf(part[((size_t)tile * PB + b) * 2 + 0] - M) * rinv;
    __syncthreads();

    const _Float16* erow = Eh + (size_t)b * PVP;
    float*          orow = out + (size_t)b * PV;

    const int NP = PV >> 1;              // 25128 pairs cover 50256
    for (int i = t; i < NP; i += 512) {
        const int c = 2 * i;
        const unsigned u = *reinterpret_cast<const unsigned*>(erow + c);
        const _Float16 e0 = ((const _Float16*)&u)[0];
        const _Float16 e1 = ((const _Float16*)&u)[1];
        const float s0 = sc[c >> 6];     // c even -> pair never crosses tile
        orow[c]     = (float)e0 * s0;
        orow[c + 1] = (float)e1 * s0;
    }
    if (t == 0)                           // tail element 50256
        orow[PV - 1] = (float)erow[PV - 1] * sc[(PV - 1) >> 6];
}

// -------------------------------------------------------------------------
extern "C" void kernel_launch(void* const* d_in, const int* in_sizes, int n_in,
                              void* d_out, int out_size, void* d_ws, size_t ws_size,
                              hipStream_t stream) {
    const int*   x_e = (const int*)d_in[0];    // [B, M, L]
    const int*   x_q = (const int*)d_in[1];    // [B, L]
    const float* emb = (const float*)d_in[2];  // [4, V, D]
    const float* W   = (const float*)d_in[3];  // [D, V]
    float*       out = (float*)d_out;          // [B, V]
    (void)n_in; (void)in_sizes; (void)out_size; (void)ws_size;

    char* p = (char*)d_ws;
    float*    M_ws = (float*)p;                p += (size_t)4 * PBM * PD * 4;   // 26.2 MB
    _Float16* uh   = (_Float16*)p;             p += (size_t)PB * PD * 2;        // 64 KB
    _Float16* Wt   = (_Float16*)p;             p += (size_t)PVP * PD * 2;       // 12.9 MB
    float*    part = (float*)p;                p += (size_t)NT * PB * 2 * 4;    // 1.6 MB
    _Float16* Eh   = (_Float16*)p;             // 256*50304*2 = 25.8 MB

    k_gatherconv<<<dim3(NCONV + 4 * NGB2), dim3(256), 0, stream>>>(
        x_e, emb, W, M_ws, Wt);
    k_hops    <<<dim3(PB),    dim3(1024), 0, stream>>>(x_q, emb, M_ws, uh);
    k_gemm_exp<<<dim3(NT, 2), dim3(128),  0, stream>>>(uh, Wt, Eh, part);
    k_scale   <<<dim3(PB),    dim3(512),  0, stream>>>(Eh, part, out);
}